// Round 3
// baseline (615.621 us; speedup 1.0000x reference)
//
#include <hip/hip_runtime.h>
#include <hip/hip_bf16.h>

#define BB 8
#define CC 128
#define HH 128
#define WW 128
#define HW (HH*WW)
#define MD 3
#define ND 49
#define WARP_WEIGHT 2.5f
#define NEG 0.1f

typedef __attribute__((ext_vector_type(8))) short bf16x8;
typedef __attribute__((ext_vector_type(4))) float f32x4;

__device__ inline ushort f2bf(float f) {
    __hip_bfloat16 h = __float2bfloat16(f);
    return *reinterpret_cast<ushort*>(&h);
}
__device__ inline float bflo(uint u) { return __uint_as_float(u << 16); }
__device__ inline float bfhi(uint u) { return __uint_as_float(u & 0xffff0000u); }

// ---------------- flow upsample (bilinear x2, align_corners=False) ----------------
__global__ void k_flow_up(const float* __restrict__ flow, float* __restrict__ flow_up) {
    const int x = threadIdx.x;      // 0..127
    const int y = blockIdx.x;       // 0..127
    const int c = blockIdx.y;       // 0..1
    const int b = blockIdx.z;       // 0..7
    const int Hs = 64, Ws = 64;
    float sy = (y + 0.5f) * 0.5f - 0.5f;
    float sx = (x + 0.5f) * 0.5f - 0.5f;
    float y0f = floorf(sy), x0f = floorf(sx);
    int y0 = (int)y0f, x0 = (int)x0f;
    float wy = sy - y0f, wx = sx - x0f;
    int y0c = min(max(y0, 0), Hs - 1), y1c = min(max(y0 + 1, 0), Hs - 1);
    int x0c = min(max(x0, 0), Ws - 1), x1c = min(max(x0 + 1, 0), Ws - 1);
    const float* src = flow + ((size_t)(b * 2 + c)) * Hs * Ws;
    float v00 = src[y0c * Ws + x0c], v01 = src[y0c * Ws + x1c];
    float v10 = src[y1c * Ws + x0c], v11 = src[y1c * Ws + x1c];
    float v = v00 * (1.f - wx) * (1.f - wy) + v01 * wx * (1.f - wy)
            + v10 * (1.f - wx) * wy + v11 * wx * wy;
    flow_up[((size_t)(b * 2 + c) * HH + y) * WW + x] = v;
}

// ---------------- backward warp -> channel-last bf16 [b][y][x][128] ----------------
__global__ __launch_bounds__(128) void k_warp(const float* __restrict__ f2,
                                              const float* __restrict__ flow_up,
                                              ushort* __restrict__ f2wcl) {
    const int x = threadIdx.x;
    const int y = blockIdx.x;
    const int b = blockIdx.y;
    const float fx = flow_up[((size_t)(b * 2 + 0) * HH + y) * WW + x] * WARP_WEIGHT;
    const float fy = flow_up[((size_t)(b * 2 + 1) * HH + y) * WW + x] * WARP_WEIGHT;
    const float sx = (float)x + fx;
    const float sy = (float)y + fy;
    float x0f = floorf(sx), y0f = floorf(sy);
    int x0 = (int)x0f, y0 = (int)y0f;
    float wx = sx - x0f, wy = sy - y0f;

    int xl  = min(max(x0, 0), WW - 2);          // pair base; x0c,x1c always in {xl, xl+1}
    int x0c = min(max(x0, 0), WW - 1);
    int x1c = min(max(x0 + 1, 0), WW - 1);
    int y0c = min(max(y0, 0), HH - 1);
    int y1c = min(max(y0 + 1, 0), HH - 1);
    bool s0 = (x0c == xl);
    bool s1 = (x1c == xl);
    bool vx0 = (x0 >= 0) & (x0 < WW);
    bool vx1 = (x0 + 1 >= 0) & (x0 + 1 < WW);
    bool vy0 = (y0 >= 0) & (y0 < HH);
    bool vy1 = (y0 + 1 >= 0) & (y0 + 1 < HH);
    float w00 = (vx0 && vy0) ? (1.f - wx) * (1.f - wy) : 0.f;
    float w01 = (vx1 && vy0) ? wx * (1.f - wy) : 0.f;
    float w10 = (vx0 && vy1) ? (1.f - wx) * wy : 0.f;
    float w11 = (vx1 && vy1) ? wx * wy : 0.f;

    const float* img = f2 + (size_t)b * CC * HW;
    const float* r0 = img + (size_t)y0c * WW + xl;
    const float* r1 = img + (size_t)y1c * WW + xl;
    ushort* dst = f2wcl + (((size_t)(b * HH + y)) * WW + x) * CC;

    for (int cb = 0; cb < CC; cb += 8) {
        ushort tmp[8];
#pragma unroll
        for (int j = 0; j < 8; j++) {
            size_t coff = (size_t)(cb + j) * HW;
            float2 p0 = *reinterpret_cast<const float2*>(r0 + coff);
            float2 p1 = *reinterpret_cast<const float2*>(r1 + coff);
            float v00 = s0 ? p0.x : p0.y;
            float v01 = s1 ? p0.x : p0.y;
            float v10 = s0 ? p1.x : p1.y;
            float v11 = s1 ? p1.x : p1.y;
            float v = v00 * w00 + v01 * w01 + v10 * w10 + v11 * w11;
            tmp[j] = f2bf(v);
        }
        *reinterpret_cast<uint4*>(dst + cb) = *reinterpret_cast<const uint4*>(tmp);
    }
}

// ---------------- 7x7 cost volume, mean over C; bf16 channel-last out ----------------
// 256 threads: lanes 0..127 = x with channels 0..63, threads 128..255 = x with ch 64..127
__global__ __launch_bounds__(256) void k_corr(const float* __restrict__ f1,
                                              const ushort* __restrict__ f2wcl,
                                              ushort* __restrict__ Ct) {
    __shared__ float red[128][ND];   // 25 KB, stride 49 (odd) -> conflict-light
    const int x = threadIdx.x & 127;
    const int half = threadIdx.x >> 7;
    const int y = blockIdx.x;
    const int b = blockIdx.y;

    float acc[ND];
#pragma unroll
    for (int i = 0; i < ND; i++) acc[i] = 0.f;

    const float* p1 = f1 + (size_t)b * CC * HW + y * WW + x;
    const ushort* base = f2wcl + (size_t)b * HW * CC;

    for (int ch = 0; ch < 8; ch++) {
        const int c0 = half * 64 + ch * 8;
        float v1[8];
#pragma unroll
        for (int j = 0; j < 8; j++) v1[j] = p1[(size_t)(c0 + j) * HW];
#pragma unroll
        for (int dy = 0; dy < 7; dy++) {
            int yy = y + dy - MD;
            if (yy < 0 || yy >= HH) continue;           // uniform branch
            const ushort* rowp = base + ((size_t)yy * WW) * CC + c0;
#pragma unroll
            for (int dx = 0; dx < 7; dx++) {
                int xx = x + dx - MD;
                uint4 u = {0u, 0u, 0u, 0u};
                if ((unsigned)xx < (unsigned)WW)
                    u = *reinterpret_cast<const uint4*>(rowp + (size_t)xx * CC);
                const int d = dy * 7 + dx;
                acc[d] += v1[0] * bflo(u.x) + v1[1] * bfhi(u.x)
                        + v1[2] * bflo(u.y) + v1[3] * bfhi(u.y)
                        + v1[4] * bflo(u.z) + v1[5] * bfhi(u.z)
                        + v1[6] * bflo(u.w) + v1[7] * bfhi(u.w);
            }
        }
    }

    if (half) {
#pragma unroll
        for (int d = 0; d < ND; d++) red[x][d] = acc[d];
    }
    __syncthreads();
    if (!half) {
        const float scale = 1.f / (float)CC;
        ushort tmp[64];
#pragma unroll
        for (int d = 0; d < ND; d++) tmp[d] = f2bf((acc[d] + red[x][d]) * scale);
#pragma unroll
        for (int d = ND; d < 64; d++) tmp[d] = 0;
        uint4* dst = reinterpret_cast<uint4*>(Ct + (((size_t)(b * HH + y)) * WW + x) * 64);
        const uint4* src = reinterpret_cast<const uint4*>(tmp);
#pragma unroll
        for (int i = 0; i < 8; i++) dst[i] = src[i];
    }
}

// ---------------- weight transpose + bf16: w[OC][IC][K][K] -> Wt[K*K][OCP][ICP] ----------------
template<int IC, int ICP, int OC, int OCP, int KK>
__global__ void k_prep_w(const float* __restrict__ w, ushort* __restrict__ Wt) {
    int e = blockIdx.x * 256 + threadIdx.x;
    const int total = KK * KK * OCP * ICP;
    if (e >= total) return;
    int ic = e % ICP;
    int oc = (e / ICP) % OCP;
    int tap = e / (ICP * OCP);
    int kh = tap / KK, kw = tap % KK;
    float v = 0.f;
    if (oc < OC && ic < IC) v = w[((oc * IC + ic) * KK + kh) * KK + kw];
    Wt[e] = f2bf(v);
}

// ---------------- implicit-GEMM MFMA conv ----------------
template<int ICP, int OCP, int OCOUT, int KK, int PAD, bool RELU, bool LAST>
__global__ __launch_bounds__(128) void k_conv_mfma(
    const ushort* __restrict__ In, const ushort* __restrict__ Wt,
    const float* __restrict__ bias, ushort* __restrict__ Out,
    const float* __restrict__ flow_up, float* __restrict__ fout)
{
    constexpr int MT = OCP / 16;
    constexpr int NCH = ICP / 32;
    const int y = blockIdx.x;
    const int b = blockIdx.y;
    const int l = threadIdx.x & 63;
    const int n0 = (threadIdx.x >> 6) * 64;
    const int lx = l & 15;
    const int lk = l >> 4;

    f32x4 acc[MT][4];
#pragma unroll
    for (int m = 0; m < MT; m++)
#pragma unroll
        for (int nt = 0; nt < 4; nt++) acc[m][nt] = (f32x4)(0.f);

    for (int kh = 0; kh < KK; kh++) {
        int yy = y + kh - PAD;
        if (yy < 0 || yy >= HH) continue;
        const ushort* inrow = In + ((size_t)(b * HH + yy)) * WW * ICP;
#pragma unroll
        for (int kw = 0; kw < KK; kw++) {
            const ushort* wtap = Wt + (size_t)(kh * KK + kw) * OCP * ICP;
#pragma unroll
            for (int ch = 0; ch < NCH; ch++) {
                const int k0 = ch * 32 + lk * 8;
                bf16x8 a[MT];
#pragma unroll
                for (int m = 0; m < MT; m++)
                    a[m] = *reinterpret_cast<const bf16x8*>(wtap + (m * 16 + lx) * ICP + k0);
#pragma unroll
                for (int nt = 0; nt < 4; nt++) {
                    int xx = n0 + nt * 16 + lx + kw - PAD;
                    bf16x8 bf = {};
                    if ((unsigned)xx < (unsigned)WW)
                        bf = *reinterpret_cast<const bf16x8*>(inrow + (size_t)xx * ICP + k0);
#pragma unroll
                    for (int m = 0; m < MT; m++)
                        acc[m][nt] = __builtin_amdgcn_mfma_f32_16x16x32_bf16(a[m], bf, acc[m][nt], 0, 0, 0);
                }
            }
        }
    }

    if (!LAST) {
#pragma unroll
        for (int m = 0; m < MT; m++) {
            const int oc0 = m * 16 + lk * 4;
            float4 bs = *reinterpret_cast<const float4*>(bias + oc0);
#pragma unroll
            for (int nt = 0; nt < 4; nt++) {
                int x = n0 + nt * 16 + lx;
                float v0 = acc[m][nt][0] + bs.x;
                float v1 = acc[m][nt][1] + bs.y;
                float v2 = acc[m][nt][2] + bs.z;
                float v3 = acc[m][nt][3] + bs.w;
                if (RELU) {
                    v0 = (v0 >= 0.f) ? v0 : NEG * v0;
                    v1 = (v1 >= 0.f) ? v1 : NEG * v1;
                    v2 = (v2 >= 0.f) ? v2 : NEG * v2;
                    v3 = (v3 >= 0.f) ? v3 : NEG * v3;
                }
                ushort4 o;
                o.x = f2bf(v0); o.y = f2bf(v1); o.z = f2bf(v2); o.w = f2bf(v3);
                *reinterpret_cast<ushort4*>(Out + (((size_t)(b * HH + y)) * WW + x) * OCOUT + oc0) = o;
            }
        }
    } else {
        if (lk == 0) {
#pragma unroll
            for (int nt = 0; nt < 4; nt++) {
                int x = n0 + nt * 16 + lx;
#pragma unroll
                for (int r = 0; r < 2; r++) {
                    size_t o = (((size_t)(b * 2 + r)) * HH + y) * WW + x;
                    fout[o] = acc[0][nt][r] + bias[r] + flow_up[o];
                }
            }
        }
    }
}

extern "C" void kernel_launch(void* const* d_in, const int* in_sizes, int n_in,
                              void* d_out, int out_size, void* d_ws, size_t ws_size,
                              hipStream_t stream) {
    const float* f1   = (const float*)d_in[0];
    const float* f2   = (const float*)d_in[1];
    const float* flow = (const float*)d_in[2];
    const float* w1   = (const float*)d_in[3];
    const float* b1   = (const float*)d_in[4];
    const float* w2   = (const float*)d_in[5];
    const float* b2   = (const float*)d_in[6];
    const float* w3   = (const float*)d_in[7];
    const float* b3   = (const float*)d_in[8];
    float* out = (float*)d_out;

    char* ws = (char*)d_ws;
    const size_t SZ_FLOWUP = (size_t)BB * 2 * HW * 4;          // 1.0 MB
    const size_t SZ_CT     = (size_t)BB * HW * 64 * 2;         // 16.8 MB
    const size_t SZ_WT1    = (size_t)9 * 64 * 64 * 2;
    const size_t SZ_WT2    = (size_t)9 * 32 * 64 * 2;
    const size_t SZ_WT3    = (size_t)25 * 16 * 32 * 2;
    const size_t SZ_F2WCL  = (size_t)BB * HW * CC * 2;         // 32 MB

    float*  flow_up = (float*)ws;                         ws += SZ_FLOWUP;
    ushort* Ct      = (ushort*)ws;                        ws += SZ_CT;
    ushort* Wt1     = (ushort*)ws;                        ws += SZ_WT1;
    ushort* Wt2     = (ushort*)ws;                        ws += SZ_WT2;
    ushort* Wt3     = (ushort*)ws;                        ws += SZ_WT3;
    ushort* f2wcl   = (ushort*)ws;                        ws += SZ_F2WCL;
    ushort* h1      = (ushort*)ws;                        // 16.8 MB
    ushort* h2      = (ushort*)(ws + (size_t)BB * HW * 64 * 2); // 8.4 MB

    k_prep_w<49, 64, 64, 64, 3><<<dim3((9 * 64 * 64 + 255) / 256), dim3(256), 0, stream>>>(w1, Wt1);
    k_prep_w<64, 64, 32, 32, 3><<<dim3((9 * 32 * 64 + 255) / 256), dim3(256), 0, stream>>>(w2, Wt2);
    k_prep_w<32, 32, 2, 16, 5><<<dim3((25 * 16 * 32 + 255) / 256), dim3(256), 0, stream>>>(w3, Wt3);

    k_flow_up<<<dim3(HH, 2, BB), dim3(WW), 0, stream>>>(flow, flow_up);
    k_warp   <<<dim3(HH, BB),    dim3(WW), 0, stream>>>(f2, flow_up, f2wcl);
    k_corr   <<<dim3(HH, BB),    dim3(256), 0, stream>>>(f1, f2wcl, Ct);

    k_conv_mfma<64, 64, 64, 3, 1, true,  false><<<dim3(HH, BB), dim3(128), 0, stream>>>(
        Ct, Wt1, b1, h1, nullptr, nullptr);
    k_conv_mfma<64, 32, 32, 3, 1, true,  false><<<dim3(HH, BB), dim3(128), 0, stream>>>(
        h1, Wt2, b2, h2, nullptr, nullptr);
    k_conv_mfma<32, 16, 2,  5, 2, false, true ><<<dim3(HH, BB), dim3(128), 0, stream>>>(
        h2, Wt3, b3, nullptr, flow_up, out);
}

// Round 4
// 307.974 us; speedup vs baseline: 1.9989x; 1.9989x over previous
//
#include <hip/hip_runtime.h>
#include <hip/hip_bf16.h>

#define BB 8
#define CC 128
#define HH 128
#define WW 128
#define HW (HH*WW)
#define MD 3
#define ND 49
#define WARP_WEIGHT 2.5f
#define NEG 0.1f

typedef __attribute__((ext_vector_type(8))) short bf16x8;
typedef __attribute__((ext_vector_type(4))) float f32x4;

__device__ inline ushort f2bf(float f) {
    __hip_bfloat16 h = __float2bfloat16(f);
    return *reinterpret_cast<ushort*>(&h);
}

// ---------------- flow upsample (bilinear x2, align_corners=False) ----------------
__global__ void k_flow_up(const float* __restrict__ flow, float* __restrict__ flow_up) {
    const int x = threadIdx.x;      // 0..127
    const int y = blockIdx.x;       // 0..127
    const int c = blockIdx.y;       // 0..1
    const int b = blockIdx.z;       // 0..7
    const int Hs = 64, Ws = 64;
    float sy = (y + 0.5f) * 0.5f - 0.5f;
    float sx = (x + 0.5f) * 0.5f - 0.5f;
    float y0f = floorf(sy), x0f = floorf(sx);
    int y0 = (int)y0f, x0 = (int)x0f;
    float wy = sy - y0f, wx = sx - x0f;
    int y0c = min(max(y0, 0), Hs - 1), y1c = min(max(y0 + 1, 0), Hs - 1);
    int x0c = min(max(x0, 0), Ws - 1), x1c = min(max(x0 + 1, 0), Ws - 1);
    const float* src = flow + ((size_t)(b * 2 + c)) * Hs * Ws;
    float v00 = src[y0c * Ws + x0c], v01 = src[y0c * Ws + x1c];
    float v10 = src[y1c * Ws + x0c], v11 = src[y1c * Ws + x1c];
    float v = v00 * (1.f - wx) * (1.f - wy) + v01 * wx * (1.f - wy)
            + v10 * (1.f - wx) * wy + v11 * wx * wy;
    flow_up[((size_t)(b * 2 + c) * HH + y) * WW + x] = v;
}

// ---------------- backward warp -> channel-last bf16 [b][y][x][128] ----------------
__global__ __launch_bounds__(128) void k_warp(const float* __restrict__ f2,
                                              const float* __restrict__ flow_up,
                                              ushort* __restrict__ f2wcl) {
    const int x = threadIdx.x;
    const int y = blockIdx.x;
    const int b = blockIdx.y;
    const float fx = flow_up[((size_t)(b * 2 + 0) * HH + y) * WW + x] * WARP_WEIGHT;
    const float fy = flow_up[((size_t)(b * 2 + 1) * HH + y) * WW + x] * WARP_WEIGHT;
    const float sx = (float)x + fx;
    const float sy = (float)y + fy;
    float x0f = floorf(sx), y0f = floorf(sy);
    int x0 = (int)x0f, y0 = (int)y0f;
    float wx = sx - x0f, wy = sy - y0f;

    int xl  = min(max(x0, 0), WW - 2);
    int x0c = min(max(x0, 0), WW - 1);
    int x1c = min(max(x0 + 1, 0), WW - 1);
    int y0c = min(max(y0, 0), HH - 1);
    int y1c = min(max(y0 + 1, 0), HH - 1);
    bool s0 = (x0c == xl);
    bool s1 = (x1c == xl);
    bool vx0 = (x0 >= 0) & (x0 < WW);
    bool vx1 = (x0 + 1 >= 0) & (x0 + 1 < WW);
    bool vy0 = (y0 >= 0) & (y0 < HH);
    bool vy1 = (y0 + 1 >= 0) & (y0 + 1 < HH);
    float w00 = (vx0 && vy0) ? (1.f - wx) * (1.f - wy) : 0.f;
    float w01 = (vx1 && vy0) ? wx * (1.f - wy) : 0.f;
    float w10 = (vx0 && vy1) ? (1.f - wx) * wy : 0.f;
    float w11 = (vx1 && vy1) ? wx * wy : 0.f;

    const float* img = f2 + (size_t)b * CC * HW;
    const float* r0 = img + (size_t)y0c * WW + xl;
    const float* r1 = img + (size_t)y1c * WW + xl;
    ushort* dst = f2wcl + (((size_t)(b * HH + y)) * WW + x) * CC;

    for (int cb = 0; cb < CC; cb += 8) {
        ushort tmp[8];
#pragma unroll
        for (int j = 0; j < 8; j++) {
            size_t coff = (size_t)(cb + j) * HW;
            float2 p0 = *reinterpret_cast<const float2*>(r0 + coff);
            float2 p1 = *reinterpret_cast<const float2*>(r1 + coff);
            float v00 = s0 ? p0.x : p0.y;
            float v01 = s1 ? p0.x : p0.y;
            float v10 = s0 ? p1.x : p1.y;
            float v11 = s1 ? p1.x : p1.y;
            float v = v00 * w00 + v01 * w01 + v10 * w10 + v11 * w11;
            tmp[j] = f2bf(v);
        }
        *reinterpret_cast<uint4*>(dst + cb) = *reinterpret_cast<const uint4*>(tmp);
    }
}

// ---------------- f1 planar f32 -> channel-last bf16 [b][y][x][128] ----------------
__global__ __launch_bounds__(128) void k_prep_f1(const float* __restrict__ f1,
                                                 ushort* __restrict__ f1cl) {
    const int x = threadIdx.x;
    const int y = blockIdx.x;
    const int b = blockIdx.y;
    const float* src = f1 + (size_t)b * CC * HW + y * WW + x;
    ushort* dst = f1cl + (((size_t)(b * HH + y)) * WW + x) * CC;
    for (int cb = 0; cb < CC; cb += 8) {
        ushort tmp[8];
#pragma unroll
        for (int j = 0; j < 8; j++) tmp[j] = f2bf(src[(size_t)(cb + j) * HW]);
        *reinterpret_cast<uint4*>(dst + cb) = *reinterpret_cast<const uint4*>(tmp);
    }
}

// ---------------- MFMA cost volume ----------------
// out[x][dx] = sum_c f1cl[x][c] * f2wcl[x+dx-3][c]  via 16x16 position cross-products.
// Wave handles one 16-x A-tile; per dy: two B-tiles (x-window [-3,12] and [13,28]),
// K=128 in 4 chunks. D[i][j]: i=(l>>4)*4+r (A row), j=l&15 (B col).
__global__ __launch_bounds__(256) void k_corr_mfma(const ushort* __restrict__ f1cl,
                                                   const ushort* __restrict__ f2wcl,
                                                   ushort* __restrict__ Ct) {
    const int w  = threadIdx.x >> 6;
    const int l  = threadIdx.x & 63;
    const int lx = l & 15;
    const int lk = l >> 4;
    const int tile = blockIdx.x * 4 + w;   // 0..7
    const int xa0 = tile * 16;
    const int y = blockIdx.y;
    const int b = blockIdx.z;

    const ushort* arow = f1cl + (((size_t)(b * HH + y)) * WW + xa0 + lx) * CC;
    bf16x8 afr[4];
#pragma unroll
    for (int kk = 0; kk < 4; kk++)
        afr[kk] = *reinterpret_cast<const bf16x8*>(arow + kk * 32 + lk * 8);

    ushort* crow = Ct + (((size_t)(b * HH + y)) * WW + xa0) * 64;
    const float scale = 1.f / (float)CC;
    const int xb0 = xa0 - 3 + lx;
    const int xb1 = xa0 + 13 + lx;

    for (int dy = 0; dy < 7; dy++) {
        int yy = y + dy - MD;
        f32x4 acc0 = (f32x4)(0.f), acc1 = (f32x4)(0.f);
        if ((unsigned)yy < (unsigned)HH) {
            const ushort* brow = f2wcl + ((size_t)(b * HH + yy)) * WW * CC;
#pragma unroll
            for (int kk = 0; kk < 4; kk++) {
                const int k0 = kk * 32 + lk * 8;
                bf16x8 b0 = {}, b1 = {};
                if ((unsigned)xb0 < (unsigned)WW)
                    b0 = *reinterpret_cast<const bf16x8*>(brow + (size_t)xb0 * CC + k0);
                if ((unsigned)xb1 < (unsigned)WW)
                    b1 = *reinterpret_cast<const bf16x8*>(brow + (size_t)xb1 * CC + k0);
                acc0 = __builtin_amdgcn_mfma_f32_16x16x32_bf16(afr[kk], b0, acc0, 0, 0, 0);
                acc1 = __builtin_amdgcn_mfma_f32_16x16x32_bf16(afr[kk], b1, acc1, 0, 0, 0);
            }
        }
        // extract diagonal band: dx = j - i - 3 (t0) / j - i + 13 (t1); d = dy*7 + dx + 3
#pragma unroll
        for (int r = 0; r < 4; r++) {
            int i = lk * 4 + r;
            int d0 = lx - i;          // dx+3 for tile0
            if (d0 >= 0 && d0 <= 6)
                crow[(size_t)i * 64 + dy * 7 + d0] = f2bf(acc0[r] * scale);
            int d1 = lx - i + 16;     // dx+3 for tile1
            if (d1 >= 0 && d1 <= 6)
                crow[(size_t)i * 64 + dy * 7 + d1] = f2bf(acc1[r] * scale);
        }
    }
}

// ---------------- weight transpose + bf16: w[OC][IC][K][K] -> Wt[K*K][OCP][ICP] ----------------
template<int IC, int ICP, int OC, int OCP, int KK>
__global__ void k_prep_w(const float* __restrict__ w, ushort* __restrict__ Wt) {
    int e = blockIdx.x * 256 + threadIdx.x;
    const int total = KK * KK * OCP * ICP;
    if (e >= total) return;
    int ic = e % ICP;
    int oc = (e / ICP) % OCP;
    int tap = e / (ICP * OCP);
    int kh = tap / KK, kw = tap % KK;
    float v = 0.f;
    if (oc < OC && ic < IC) v = w[((oc * IC + ic) * KK + kh) * KK + kw];
    Wt[e] = f2bf(v);
}

// ---------------- implicit-GEMM MFMA conv ----------------
template<int ICP, int OCP, int OCOUT, int KK, int PAD, bool RELU, bool LAST>
__global__ __launch_bounds__(128) void k_conv_mfma(
    const ushort* __restrict__ In, const ushort* __restrict__ Wt,
    const float* __restrict__ bias, ushort* __restrict__ Out,
    const float* __restrict__ flow_up, float* __restrict__ fout)
{
    constexpr int MT = OCP / 16;
    constexpr int NCH = ICP / 32;
    const int y = blockIdx.x;
    const int b = blockIdx.y;
    const int l = threadIdx.x & 63;
    const int n0 = (threadIdx.x >> 6) * 64;
    const int lx = l & 15;
    const int lk = l >> 4;

    f32x4 acc[MT][4];
#pragma unroll
    for (int m = 0; m < MT; m++)
#pragma unroll
        for (int nt = 0; nt < 4; nt++) acc[m][nt] = (f32x4)(0.f);

    for (int kh = 0; kh < KK; kh++) {
        int yy = y + kh - PAD;
        if (yy < 0 || yy >= HH) continue;
        const ushort* inrow = In + ((size_t)(b * HH + yy)) * WW * ICP;
#pragma unroll
        for (int kw = 0; kw < KK; kw++) {
            const ushort* wtap = Wt + (size_t)(kh * KK + kw) * OCP * ICP;
#pragma unroll
            for (int ch = 0; ch < NCH; ch++) {
                const int k0 = ch * 32 + lk * 8;
                bf16x8 a[MT];
#pragma unroll
                for (int m = 0; m < MT; m++)
                    a[m] = *reinterpret_cast<const bf16x8*>(wtap + (m * 16 + lx) * ICP + k0);
#pragma unroll
                for (int nt = 0; nt < 4; nt++) {
                    int xx = n0 + nt * 16 + lx + kw - PAD;
                    bf16x8 bf = {};
                    if ((unsigned)xx < (unsigned)WW)
                        bf = *reinterpret_cast<const bf16x8*>(inrow + (size_t)xx * ICP + k0);
#pragma unroll
                    for (int m = 0; m < MT; m++)
                        acc[m][nt] = __builtin_amdgcn_mfma_f32_16x16x32_bf16(a[m], bf, acc[m][nt], 0, 0, 0);
                }
            }
        }
    }

    if (!LAST) {
#pragma unroll
        for (int m = 0; m < MT; m++) {
            const int oc0 = m * 16 + lk * 4;
            float4 bs = *reinterpret_cast<const float4*>(bias + oc0);
#pragma unroll
            for (int nt = 0; nt < 4; nt++) {
                int x = n0 + nt * 16 + lx;
                float v0 = acc[m][nt][0] + bs.x;
                float v1 = acc[m][nt][1] + bs.y;
                float v2 = acc[m][nt][2] + bs.z;
                float v3 = acc[m][nt][3] + bs.w;
                if (RELU) {
                    v0 = (v0 >= 0.f) ? v0 : NEG * v0;
                    v1 = (v1 >= 0.f) ? v1 : NEG * v1;
                    v2 = (v2 >= 0.f) ? v2 : NEG * v2;
                    v3 = (v3 >= 0.f) ? v3 : NEG * v3;
                }
                ushort4 o;
                o.x = f2bf(v0); o.y = f2bf(v1); o.z = f2bf(v2); o.w = f2bf(v3);
                *reinterpret_cast<ushort4*>(Out + (((size_t)(b * HH + y)) * WW + x) * OCOUT + oc0) = o;
            }
        }
    } else {
        if (lk == 0) {
#pragma unroll
            for (int nt = 0; nt < 4; nt++) {
                int x = n0 + nt * 16 + lx;
#pragma unroll
                for (int r = 0; r < 2; r++) {
                    size_t o = (((size_t)(b * 2 + r)) * HH + y) * WW + x;
                    fout[o] = acc[0][nt][r] + bias[r] + flow_up[o];
                }
            }
        }
    }
}

extern "C" void kernel_launch(void* const* d_in, const int* in_sizes, int n_in,
                              void* d_out, int out_size, void* d_ws, size_t ws_size,
                              hipStream_t stream) {
    const float* f1   = (const float*)d_in[0];
    const float* f2   = (const float*)d_in[1];
    const float* flow = (const float*)d_in[2];
    const float* w1   = (const float*)d_in[3];
    const float* b1   = (const float*)d_in[4];
    const float* w2   = (const float*)d_in[5];
    const float* b2   = (const float*)d_in[6];
    const float* w3   = (const float*)d_in[7];
    const float* b3   = (const float*)d_in[8];
    float* out = (float*)d_out;

    char* ws = (char*)d_ws;
    const size_t SZ_FLOWUP = (size_t)BB * 2 * HW * 4;          // 1.0 MB
    const size_t SZ_CT     = (size_t)BB * HW * 64 * 2;         // 16.8 MB
    const size_t SZ_WT1    = (size_t)9 * 64 * 64 * 2;
    const size_t SZ_WT2    = (size_t)9 * 32 * 64 * 2;
    const size_t SZ_WT3    = (size_t)25 * 16 * 32 * 2;
    const size_t SZ_F2WCL  = (size_t)BB * HW * CC * 2;         // 32 MB
    const size_t SZ_F1CL   = (size_t)BB * HW * CC * 2;         // 32 MB (aliased by h1/h2 later)

    float*  flow_up = (float*)ws;                         ws += SZ_FLOWUP;
    ushort* Ct      = (ushort*)ws;                        ws += SZ_CT;
    ushort* Wt1     = (ushort*)ws;                        ws += SZ_WT1;
    ushort* Wt2     = (ushort*)ws;                        ws += SZ_WT2;
    ushort* Wt3     = (ushort*)ws;                        ws += SZ_WT3;
    ushort* f2wcl   = (ushort*)ws;                        ws += SZ_F2WCL;
    ushort* f1cl    = (ushort*)ws;                        // 32 MB
    ushort* h1      = f1cl;                               // 16.8 MB (f1cl dead after corr)
    ushort* h2      = (ushort*)((char*)f1cl + (size_t)BB * HW * 64 * 2); // 8.4 MB

    k_prep_w<49, 64, 64, 64, 3><<<dim3((9 * 64 * 64 + 255) / 256), dim3(256), 0, stream>>>(w1, Wt1);
    k_prep_w<64, 64, 32, 32, 3><<<dim3((9 * 32 * 64 + 255) / 256), dim3(256), 0, stream>>>(w2, Wt2);
    k_prep_w<32, 32, 2, 16, 5><<<dim3((25 * 16 * 32 + 255) / 256), dim3(256), 0, stream>>>(w3, Wt3);

    k_flow_up<<<dim3(HH, 2, BB), dim3(WW), 0, stream>>>(flow, flow_up);
    k_warp   <<<dim3(HH, BB),    dim3(WW), 0, stream>>>(f2, flow_up, f2wcl);
    k_prep_f1<<<dim3(HH, BB),    dim3(WW), 0, stream>>>(f1, f1cl);
    k_corr_mfma<<<dim3(2, HH, BB), dim3(256), 0, stream>>>(f1cl, f2wcl, Ct);

    k_conv_mfma<64, 64, 64, 3, 1, true,  false><<<dim3(HH, BB), dim3(128), 0, stream>>>(
        Ct, Wt1, b1, h1, nullptr, nullptr);
    k_conv_mfma<64, 32, 32, 3, 1, true,  false><<<dim3(HH, BB), dim3(128), 0, stream>>>(
        h1, Wt2, b2, h2, nullptr, nullptr);
    k_conv_mfma<32, 16, 2,  5, 2, false, true ><<<dim3(HH, BB), dim3(128), 0, stream>>>(
        h2, Wt3, b3, nullptr, flow_up, out);
}

// Round 5
// 242.695 us; speedup vs baseline: 2.5366x; 1.2690x over previous
//
#include <hip/hip_runtime.h>
#include <hip/hip_bf16.h>

#define BB 8
#define CC 128
#define HH 128
#define WW 128
#define HW (HH*WW)
#define MD 3
#define ND 49
#define WARP_WEIGHT 2.5f
#define NEG 0.1f

typedef __attribute__((ext_vector_type(8))) short bf16x8;
typedef __attribute__((ext_vector_type(4))) float f32x4;

__device__ inline ushort f2bf(float f) {
    __hip_bfloat16 h = __float2bfloat16(f);
    return *reinterpret_cast<ushort*>(&h);
}

// g8 layout: F[b][y][g][x][8] ushort, g = c/8 (16 groups of 8 channels)
#define G8_IDX(b, y, g) ((((size_t)((b) * HH + (y)) * 16) + (g)) * (WW * 8))

// ---------------- flow upsample (bilinear x2, align_corners=False) ----------------
__global__ void k_flow_up(const float* __restrict__ flow, float* __restrict__ flow_up) {
    const int x = threadIdx.x;
    const int y = blockIdx.x;
    const int c = blockIdx.y;
    const int b = blockIdx.z;
    const int Hs = 64, Ws = 64;
    float sy = (y + 0.5f) * 0.5f - 0.5f;
    float sx = (x + 0.5f) * 0.5f - 0.5f;
    float y0f = floorf(sy), x0f = floorf(sx);
    int y0 = (int)y0f, x0 = (int)x0f;
    float wy = sy - y0f, wx = sx - x0f;
    int y0c = min(max(y0, 0), Hs - 1), y1c = min(max(y0 + 1, 0), Hs - 1);
    int x0c = min(max(x0, 0), Ws - 1), x1c = min(max(x0 + 1, 0), Ws - 1);
    const float* src = flow + ((size_t)(b * 2 + c)) * Hs * Ws;
    float v00 = src[y0c * Ws + x0c], v01 = src[y0c * Ws + x1c];
    float v10 = src[y1c * Ws + x0c], v11 = src[y1c * Ws + x1c];
    float v = v00 * (1.f - wx) * (1.f - wy) + v01 * wx * (1.f - wy)
            + v10 * (1.f - wx) * wy + v11 * wx * wy;
    flow_up[((size_t)(b * 2 + c) * HH + y) * WW + x] = v;
}

// ---------------- backward warp -> g8 bf16; XCD-banded y, 32 ch / block ----------------
__global__ __launch_bounds__(256) void k_warp(const float* __restrict__ f2,
                                              const float* __restrict__ flow_up,
                                              ushort* __restrict__ f2g8) {
    const int bid = blockIdx.x;            // 4096 blocks
    const int k = bid & 7;                 // XCD slot (round-robin dispatch)
    const int t = bid >> 3;                // 0..511
    const int y = k * 16 + (t & 15);       // XCD k owns rows [16k, 16k+16)
    const int b = (t >> 4) & 7;
    const int chunk = t >> 7;              // 0..3 (32 channels each)
    const int x  = threadIdx.x & 127;
    const int cg = threadIdx.x >> 7;       // 0..1
    const int c0 = chunk * 32 + cg * 16;   // this thread: 16 channels

    const float fx = flow_up[((size_t)(b * 2 + 0) * HH + y) * WW + x] * WARP_WEIGHT;
    const float fy = flow_up[((size_t)(b * 2 + 1) * HH + y) * WW + x] * WARP_WEIGHT;
    const float sx = (float)x + fx;
    const float sy = (float)y + fy;
    float x0f = floorf(sx), y0f = floorf(sy);
    int x0 = (int)x0f, y0 = (int)y0f;
    float wx = sx - x0f, wy = sy - y0f;

    int xl  = min(max(x0, 0), WW - 2);
    int x0c = min(max(x0, 0), WW - 1);
    int x1c = min(max(x0 + 1, 0), WW - 1);
    int y0c = min(max(y0, 0), HH - 1);
    int y1c = min(max(y0 + 1, 0), HH - 1);
    bool s0 = (x0c == xl);
    bool s1 = (x1c == xl);
    bool vx0 = (x0 >= 0) & (x0 < WW);
    bool vx1 = (x0 + 1 >= 0) & (x0 + 1 < WW);
    bool vy0 = (y0 >= 0) & (y0 < HH);
    bool vy1 = (y0 + 1 >= 0) & (y0 + 1 < HH);
    float w00 = (vx0 && vy0) ? (1.f - wx) * (1.f - wy) : 0.f;
    float w01 = (vx1 && vy0) ? wx * (1.f - wy) : 0.f;
    float w10 = (vx0 && vy1) ? (1.f - wx) * wy : 0.f;
    float w11 = (vx1 && vy1) ? wx * wy : 0.f;

    const float* img = f2 + (size_t)b * CC * HW;
    const float* r0 = img + (size_t)y0c * WW + xl;
    const float* r1 = img + (size_t)y1c * WW + xl;

#pragma unroll
    for (int gi = 0; gi < 2; gi++) {
        ushort tmp[8];
#pragma unroll
        for (int j = 0; j < 8; j++) {
            size_t coff = (size_t)(c0 + gi * 8 + j) * HW;
            float2 p0 = *reinterpret_cast<const float2*>(r0 + coff);
            float2 p1 = *reinterpret_cast<const float2*>(r1 + coff);
            float v00 = s0 ? p0.x : p0.y;
            float v01 = s1 ? p0.x : p0.y;
            float v10 = s0 ? p1.x : p1.y;
            float v11 = s1 ? p1.x : p1.y;
            tmp[j] = f2bf(v00 * w00 + v01 * w01 + v10 * w10 + v11 * w11);
        }
        *reinterpret_cast<uint4*>(f2g8 + G8_IDX(b, y, (c0 >> 3) + gi) + x * 8) =
            *reinterpret_cast<const uint4*>(tmp);
    }
}

// ---------------- f1 planar f32 -> g8 bf16 ----------------
__global__ __launch_bounds__(256) void k_prep_f1(const float* __restrict__ f1,
                                                 ushort* __restrict__ f1g8) {
    const int bid = blockIdx.x;            // 4096
    const int y = bid & 127;
    const int b = (bid >> 7) & 7;
    const int chunk = bid >> 10;           // 0..3
    const int x  = threadIdx.x & 127;
    const int cg = threadIdx.x >> 7;
    const int c0 = chunk * 32 + cg * 16;
    const float* src = f1 + ((size_t)b * CC + c0) * HW + y * WW + x;
#pragma unroll
    for (int gi = 0; gi < 2; gi++) {
        ushort tmp[8];
#pragma unroll
        for (int j = 0; j < 8; j++) tmp[j] = f2bf(src[(size_t)(gi * 8 + j) * HW]);
        *reinterpret_cast<uint4*>(f1g8 + G8_IDX(b, y, (c0 >> 3) + gi) + x * 8) =
            *reinterpret_cast<const uint4*>(tmp);
    }
}

// ---------------- MFMA cost volume (g8 inputs) ----------------
__global__ __launch_bounds__(256) void k_corr_mfma(const ushort* __restrict__ f1g8,
                                                   const ushort* __restrict__ f2g8,
                                                   ushort* __restrict__ Ct) {
    const int w  = threadIdx.x >> 6;
    const int l  = threadIdx.x & 63;
    const int lx = l & 15;
    const int lk = l >> 4;
    const int tile = blockIdx.x * 4 + w;   // 0..7
    const int xa0 = tile * 16;
    const int y = blockIdx.y;
    const int b = blockIdx.z;

    bf16x8 afr[4];
#pragma unroll
    for (int kk = 0; kk < 4; kk++)
        afr[kk] = *reinterpret_cast<const bf16x8*>(
            f1g8 + G8_IDX(b, y, kk * 4 + lk) + (xa0 + lx) * 8);

    ushort* crow = Ct + (((size_t)(b * HH + y)) * WW + xa0) * 64;
    const float scale = 1.f / (float)CC;
    const int xb0 = xa0 - 3 + lx;
    const int xb1 = xa0 + 13 + lx;

    for (int dy = 0; dy < 7; dy++) {
        int yy = y + dy - MD;
        f32x4 acc0 = (f32x4)(0.f), acc1 = (f32x4)(0.f);
        if ((unsigned)yy < (unsigned)HH) {
#pragma unroll
            for (int kk = 0; kk < 4; kk++) {
                const ushort* grp = f2g8 + G8_IDX(b, yy, kk * 4 + lk);
                bf16x8 b0 = {}, b1 = {};
                if ((unsigned)xb0 < (unsigned)WW)
                    b0 = *reinterpret_cast<const bf16x8*>(grp + xb0 * 8);
                if ((unsigned)xb1 < (unsigned)WW)
                    b1 = *reinterpret_cast<const bf16x8*>(grp + xb1 * 8);
                acc0 = __builtin_amdgcn_mfma_f32_16x16x32_bf16(afr[kk], b0, acc0, 0, 0, 0);
                acc1 = __builtin_amdgcn_mfma_f32_16x16x32_bf16(afr[kk], b1, acc1, 0, 0, 0);
            }
        }
#pragma unroll
        for (int r = 0; r < 4; r++) {
            int i = lk * 4 + r;
            int d0 = lx - i;
            if (d0 >= 0 && d0 <= 6)
                crow[(size_t)i * 64 + dy * 7 + d0] = f2bf(acc0[r] * scale);
            int d1 = lx - i + 16;
            if (d1 >= 0 && d1 <= 6)
                crow[(size_t)i * 64 + dy * 7 + d1] = f2bf(acc1[r] * scale);
        }
    }
}

// ---------------- weight transpose + bf16: w[OC][IC][K][K] -> Wt[K*K][OCP][ICP] ----------------
template<int IC, int ICP, int OC, int OCP, int KK>
__global__ void k_prep_w(const float* __restrict__ w, ushort* __restrict__ Wt) {
    int e = blockIdx.x * 256 + threadIdx.x;
    const int total = KK * KK * OCP * ICP;
    if (e >= total) return;
    int ic = e % ICP;
    int oc = (e / ICP) % OCP;
    int tap = e / (ICP * OCP);
    int kh = tap / KK, kw = tap % KK;
    float v = 0.f;
    if (oc < OC && ic < IC) v = w[((oc * IC + ic) * KK + kh) * KK + kw];
    Wt[e] = f2bf(v);
}

// ---------------- implicit-GEMM MFMA conv (4 waves, 32 px each) ----------------
template<int ICP, int OCP, int OCOUT, int KK, int PAD, bool RELU, bool LAST>
__global__ __launch_bounds__(256) void k_conv_mfma(
    const ushort* __restrict__ In, const ushort* __restrict__ Wt,
    const float* __restrict__ bias, ushort* __restrict__ Out,
    const float* __restrict__ flow_up, float* __restrict__ fout)
{
    constexpr int MT = OCP / 16;
    constexpr int NCH = ICP / 32;
    constexpr int NT = 2;
    const int y = blockIdx.x;
    const int b = blockIdx.y;
    const int l = threadIdx.x & 63;
    const int n0 = (threadIdx.x >> 6) * (16 * NT);
    const int lx = l & 15;
    const int lk = l >> 4;

    f32x4 acc[MT][NT];
#pragma unroll
    for (int m = 0; m < MT; m++)
#pragma unroll
        for (int nt = 0; nt < NT; nt++) acc[m][nt] = (f32x4)(0.f);

    for (int kh = 0; kh < KK; kh++) {
        int yy = y + kh - PAD;
        if (yy < 0 || yy >= HH) continue;
        const ushort* inrow = In + ((size_t)(b * HH + yy)) * WW * ICP;
#pragma unroll
        for (int kw = 0; kw < KK; kw++) {
            const ushort* wtap = Wt + (size_t)(kh * KK + kw) * OCP * ICP;
#pragma unroll
            for (int ch = 0; ch < NCH; ch++) {
                const int k0 = ch * 32 + lk * 8;
                bf16x8 a[MT];
#pragma unroll
                for (int m = 0; m < MT; m++)
                    a[m] = *reinterpret_cast<const bf16x8*>(wtap + (m * 16 + lx) * ICP + k0);
#pragma unroll
                for (int nt = 0; nt < NT; nt++) {
                    int xx = n0 + nt * 16 + lx + kw - PAD;
                    bf16x8 bf = {};
                    if ((unsigned)xx < (unsigned)WW)
                        bf = *reinterpret_cast<const bf16x8*>(inrow + (size_t)xx * ICP + k0);
#pragma unroll
                    for (int m = 0; m < MT; m++)
                        acc[m][nt] = __builtin_amdgcn_mfma_f32_16x16x32_bf16(a[m], bf, acc[m][nt], 0, 0, 0);
                }
            }
        }
    }

    if (!LAST) {
#pragma unroll
        for (int m = 0; m < MT; m++) {
            const int oc0 = m * 16 + lk * 4;
            float4 bs = *reinterpret_cast<const float4*>(bias + oc0);
#pragma unroll
            for (int nt = 0; nt < NT; nt++) {
                int x = n0 + nt * 16 + lx;
                float v0 = acc[m][nt][0] + bs.x;
                float v1 = acc[m][nt][1] + bs.y;
                float v2 = acc[m][nt][2] + bs.z;
                float v3 = acc[m][nt][3] + bs.w;
                if (RELU) {
                    v0 = (v0 >= 0.f) ? v0 : NEG * v0;
                    v1 = (v1 >= 0.f) ? v1 : NEG * v1;
                    v2 = (v2 >= 0.f) ? v2 : NEG * v2;
                    v3 = (v3 >= 0.f) ? v3 : NEG * v3;
                }
                ushort4 o;
                o.x = f2bf(v0); o.y = f2bf(v1); o.z = f2bf(v2); o.w = f2bf(v3);
                *reinterpret_cast<ushort4*>(Out + (((size_t)(b * HH + y)) * WW + x) * OCOUT + oc0) = o;
            }
        }
    } else {
        if (lk == 0) {
#pragma unroll
            for (int nt = 0; nt < NT; nt++) {
                int x = n0 + nt * 16 + lx;
#pragma unroll
                for (int r = 0; r < 2; r++) {
                    size_t o = (((size_t)(b * 2 + r)) * HH + y) * WW + x;
                    fout[o] = acc[0][nt][r] + bias[r] + flow_up[o];
                }
            }
        }
    }
}

extern "C" void kernel_launch(void* const* d_in, const int* in_sizes, int n_in,
                              void* d_out, int out_size, void* d_ws, size_t ws_size,
                              hipStream_t stream) {
    const float* f1   = (const float*)d_in[0];
    const float* f2   = (const float*)d_in[1];
    const float* flow = (const float*)d_in[2];
    const float* w1   = (const float*)d_in[3];
    const float* b1   = (const float*)d_in[4];
    const float* w2   = (const float*)d_in[5];
    const float* b2   = (const float*)d_in[6];
    const float* w3   = (const float*)d_in[7];
    const float* b3   = (const float*)d_in[8];
    float* out = (float*)d_out;

    char* ws = (char*)d_ws;
    const size_t SZ_FLOWUP = (size_t)BB * 2 * HW * 4;          // 1.0 MB
    const size_t SZ_CT     = (size_t)BB * HW * 64 * 2;         // 16.8 MB
    const size_t SZ_WT1    = (size_t)9 * 64 * 64 * 2;
    const size_t SZ_WT2    = (size_t)9 * 32 * 64 * 2;
    const size_t SZ_WT3    = (size_t)25 * 16 * 32 * 2;
    const size_t SZ_F2G8   = (size_t)BB * HW * CC * 2;         // 33.5 MB

    float*  flow_up = (float*)ws;                         ws += SZ_FLOWUP;
    ushort* Ct      = (ushort*)ws;                        ws += SZ_CT;
    ushort* Wt1     = (ushort*)ws;                        ws += SZ_WT1;
    ushort* Wt2     = (ushort*)ws;                        ws += SZ_WT2;
    ushort* Wt3     = (ushort*)ws;                        ws += SZ_WT3;
    ushort* f2g8    = (ushort*)ws;                        ws += SZ_F2G8;
    ushort* f1g8    = (ushort*)ws;                        // 33.5 MB
    ushort* h1      = f1g8;                               // aliases f1g8 (dead after corr)
    ushort* h2      = (ushort*)((char*)f1g8 + (size_t)BB * HW * 64 * 2);

    k_prep_w<49, 64, 64, 64, 3><<<dim3((9 * 64 * 64 + 255) / 256), dim3(256), 0, stream>>>(w1, Wt1);
    k_prep_w<64, 64, 32, 32, 3><<<dim3((9 * 32 * 64 + 255) / 256), dim3(256), 0, stream>>>(w2, Wt2);
    k_prep_w<32, 32, 2, 16, 5><<<dim3((25 * 16 * 32 + 255) / 256), dim3(256), 0, stream>>>(w3, Wt3);

    k_flow_up<<<dim3(HH, 2, BB), dim3(WW), 0, stream>>>(flow, flow_up);
    k_warp   <<<dim3(HH * BB * 4 / 8 * 8 / 256 * 256 ? 4096 : 4096), dim3(256), 0, stream>>>(f2, flow_up, f2g8);
    k_prep_f1<<<dim3(4096), dim3(256), 0, stream>>>(f1, f1g8);
    k_corr_mfma<<<dim3(2, HH, BB), dim3(256), 0, stream>>>(f1g8, f2g8, Ct);

    k_conv_mfma<64, 64, 64, 3, 1, true,  false><<<dim3(HH, BB), dim3(256), 0, stream>>>(
        Ct, Wt1, b1, h1, nullptr, nullptr);
    k_conv_mfma<64, 32, 32, 3, 1, true,  false><<<dim3(HH, BB), dim3(256), 0, stream>>>(
        h1, Wt2, b2, h2, nullptr, nullptr);
    k_conv_mfma<32, 16, 2,  5, 2, false, true ><<<dim3(HH, BB), dim3(256), 0, stream>>>(
        h2, Wt3, b3, nullptr, flow_up, out);
}

// Round 6
// 206.145 us; speedup vs baseline: 2.9864x; 1.1773x over previous
//
#include <hip/hip_runtime.h>
#include <hip/hip_bf16.h>

#define BB 8
#define CC 128
#define HH 128
#define WW 128
#define HW (HH*WW)
#define MD 3
#define ND 49
#define WARP_WEIGHT 2.5f
#define NEG 0.1f

typedef __attribute__((ext_vector_type(8))) short bf16x8;
typedef __attribute__((ext_vector_type(4))) float f32x4;

__device__ inline ushort f2bf(float f) {
    __hip_bfloat16 h = __float2bfloat16(f);
    return *reinterpret_cast<ushort*>(&h);
}

// g8 layout: F[b][y][g][x][8] ushort, g = c/8 (16 groups of 8 channels)
#define G8_IDX(b, y, g) ((((size_t)((b) * HH + (y)) * 16) + (g)) * (WW * 8))

// ---------------- flow upsample (bilinear x2, align_corners=False) ----------------
__global__ void k_flow_up(const float* __restrict__ flow, float* __restrict__ flow_up) {
    const int x = threadIdx.x;
    const int y = blockIdx.x;
    const int c = blockIdx.y;
    const int b = blockIdx.z;
    const int Hs = 64, Ws = 64;
    float sy = (y + 0.5f) * 0.5f - 0.5f;
    float sx = (x + 0.5f) * 0.5f - 0.5f;
    float y0f = floorf(sy), x0f = floorf(sx);
    int y0 = (int)y0f, x0 = (int)x0f;
    float wy = sy - y0f, wx = sx - x0f;
    int y0c = min(max(y0, 0), Hs - 1), y1c = min(max(y0 + 1, 0), Hs - 1);
    int x0c = min(max(x0, 0), Ws - 1), x1c = min(max(x0 + 1, 0), Ws - 1);
    const float* src = flow + ((size_t)(b * 2 + c)) * Hs * Ws;
    float v00 = src[y0c * Ws + x0c], v01 = src[y0c * Ws + x1c];
    float v10 = src[y1c * Ws + x0c], v11 = src[y1c * Ws + x1c];
    float v = v00 * (1.f - wx) * (1.f - wy) + v01 * wx * (1.f - wy)
            + v10 * (1.f - wx) * wy + v11 * wx * wy;
    flow_up[((size_t)(b * 2 + c) * HH + y) * WW + x] = v;
}

// ---------------- backward warp -> g8 bf16; XCD-banded y, 32 ch / block ----------------
__global__ __launch_bounds__(256) void k_warp(const float* __restrict__ f2,
                                              const float* __restrict__ flow_up,
                                              ushort* __restrict__ f2g8) {
    const int bid = blockIdx.x;            // 4096 blocks
    const int k = bid & 7;                 // XCD slot (round-robin dispatch)
    const int t = bid >> 3;                // 0..511
    const int y = k * 16 + (t & 15);       // XCD k owns rows [16k, 16k+16)
    const int b = (t >> 4) & 7;
    const int chunk = t >> 7;              // 0..3 (32 channels each)
    const int x  = threadIdx.x & 127;
    const int cg = threadIdx.x >> 7;       // 0..1
    const int c0 = chunk * 32 + cg * 16;   // this thread: 16 channels

    const float fx = flow_up[((size_t)(b * 2 + 0) * HH + y) * WW + x] * WARP_WEIGHT;
    const float fy = flow_up[((size_t)(b * 2 + 1) * HH + y) * WW + x] * WARP_WEIGHT;
    const float sx = (float)x + fx;
    const float sy = (float)y + fy;
    float x0f = floorf(sx), y0f = floorf(sy);
    int x0 = (int)x0f, y0 = (int)y0f;
    float wx = sx - x0f, wy = sy - y0f;

    int xl  = min(max(x0, 0), WW - 2);
    int x0c = min(max(x0, 0), WW - 1);
    int x1c = min(max(x0 + 1, 0), WW - 1);
    int y0c = min(max(y0, 0), HH - 1);
    int y1c = min(max(y0 + 1, 0), HH - 1);
    bool s0 = (x0c == xl);
    bool s1 = (x1c == xl);
    bool vx0 = (x0 >= 0) & (x0 < WW);
    bool vx1 = (x0 + 1 >= 0) & (x0 + 1 < WW);
    bool vy0 = (y0 >= 0) & (y0 < HH);
    bool vy1 = (y0 + 1 >= 0) & (y0 + 1 < HH);
    float w00 = (vx0 && vy0) ? (1.f - wx) * (1.f - wy) : 0.f;
    float w01 = (vx1 && vy0) ? wx * (1.f - wy) : 0.f;
    float w10 = (vx0 && vy1) ? (1.f - wx) * wy : 0.f;
    float w11 = (vx1 && vy1) ? wx * wy : 0.f;

    const float* img = f2 + (size_t)b * CC * HW;
    const float* r0 = img + (size_t)y0c * WW + xl;
    const float* r1 = img + (size_t)y1c * WW + xl;

#pragma unroll
    for (int gi = 0; gi < 2; gi++) {
        ushort tmp[8];
#pragma unroll
        for (int j = 0; j < 8; j++) {
            size_t coff = (size_t)(c0 + gi * 8 + j) * HW;
            float2 p0 = *reinterpret_cast<const float2*>(r0 + coff);
            float2 p1 = *reinterpret_cast<const float2*>(r1 + coff);
            float v00 = s0 ? p0.x : p0.y;
            float v01 = s1 ? p0.x : p0.y;
            float v10 = s0 ? p1.x : p1.y;
            float v11 = s1 ? p1.x : p1.y;
            tmp[j] = f2bf(v00 * w00 + v01 * w01 + v10 * w10 + v11 * w11);
        }
        *reinterpret_cast<uint4*>(f2g8 + G8_IDX(b, y, (c0 >> 3) + gi) + x * 8) =
            *reinterpret_cast<const uint4*>(tmp);
    }
}

// ---------------- f1 planar f32 -> g8 bf16 ----------------
__global__ __launch_bounds__(256) void k_prep_f1(const float* __restrict__ f1,
                                                 ushort* __restrict__ f1g8) {
    const int bid = blockIdx.x;            // 4096
    const int y = bid & 127;
    const int b = (bid >> 7) & 7;
    const int chunk = bid >> 10;           // 0..3
    const int x  = threadIdx.x & 127;
    const int cg = threadIdx.x >> 7;
    const int c0 = chunk * 32 + cg * 16;
    const float* src = f1 + ((size_t)b * CC + c0) * HW + y * WW + x;
#pragma unroll
    for (int gi = 0; gi < 2; gi++) {
        ushort tmp[8];
#pragma unroll
        for (int j = 0; j < 8; j++) tmp[j] = f2bf(src[(size_t)(gi * 8 + j) * HW]);
        *reinterpret_cast<uint4*>(f1g8 + G8_IDX(b, y, (c0 >> 3) + gi) + x * 8) =
            *reinterpret_cast<const uint4*>(tmp);
    }
}

// ---------------- MFMA cost volume (g8 inputs) ----------------
__global__ __launch_bounds__(256) void k_corr_mfma(const ushort* __restrict__ f1g8,
                                                   const ushort* __restrict__ f2g8,
                                                   ushort* __restrict__ Ct) {
    const int w  = threadIdx.x >> 6;
    const int l  = threadIdx.x & 63;
    const int lx = l & 15;
    const int lk = l >> 4;
    const int tile = blockIdx.x * 4 + w;   // 0..7
    const int xa0 = tile * 16;
    const int y = blockIdx.y;
    const int b = blockIdx.z;

    bf16x8 afr[4];
#pragma unroll
    for (int kk = 0; kk < 4; kk++)
        afr[kk] = *reinterpret_cast<const bf16x8*>(
            f1g8 + G8_IDX(b, y, kk * 4 + lk) + (xa0 + lx) * 8);

    ushort* crow = Ct + (((size_t)(b * HH + y)) * WW + xa0) * 64;
    const float scale = 1.f / (float)CC;
    const int xb0 = xa0 - 3 + lx;
    const int xb1 = xa0 + 13 + lx;

    for (int dy = 0; dy < 7; dy++) {
        int yy = y + dy - MD;
        f32x4 acc0 = (f32x4)(0.f), acc1 = (f32x4)(0.f);
        if ((unsigned)yy < (unsigned)HH) {
#pragma unroll
            for (int kk = 0; kk < 4; kk++) {
                const ushort* grp = f2g8 + G8_IDX(b, yy, kk * 4 + lk);
                bf16x8 b0 = {}, b1 = {};
                if ((unsigned)xb0 < (unsigned)WW)
                    b0 = *reinterpret_cast<const bf16x8*>(grp + xb0 * 8);
                if ((unsigned)xb1 < (unsigned)WW)
                    b1 = *reinterpret_cast<const bf16x8*>(grp + xb1 * 8);
                acc0 = __builtin_amdgcn_mfma_f32_16x16x32_bf16(afr[kk], b0, acc0, 0, 0, 0);
                acc1 = __builtin_amdgcn_mfma_f32_16x16x32_bf16(afr[kk], b1, acc1, 0, 0, 0);
            }
        }
#pragma unroll
        for (int r = 0; r < 4; r++) {
            int i = lk * 4 + r;
            int d0 = lx - i;
            if (d0 >= 0 && d0 <= 6)
                crow[(size_t)i * 64 + dy * 7 + d0] = f2bf(acc0[r] * scale);
            int d1 = lx - i + 16;
            if (d1 >= 0 && d1 <= 6)
                crow[(size_t)i * 64 + dy * 7 + d1] = f2bf(acc1[r] * scale);
        }
    }
}

// ---------------- weight transpose + bf16: w[OC][IC][K][K] -> Wt[K*K][OCP][ICP] ----------------
template<int IC, int ICP, int OC, int OCP, int KK>
__global__ void k_prep_w(const float* __restrict__ w, ushort* __restrict__ Wt) {
    int e = blockIdx.x * 256 + threadIdx.x;
    const int total = KK * KK * OCP * ICP;
    if (e >= total) return;
    int ic = e % ICP;
    int oc = (e / ICP) % OCP;
    int tap = e / (ICP * OCP);
    int kh = tap / KK, kw = tap % KK;
    float v = 0.f;
    if (oc < OC && ic < IC) v = w[((oc * IC + ic) * KK + kh) * KK + kw];
    Wt[e] = f2bf(v);
}

// ---------------- implicit-GEMM MFMA conv, NT=4, double-buffered tap prefetch ----------------
// Block: 4 waves over 2 rows; wave (w>>1) = row offset, (w&1) = 64-px half.
template<int ICP, int OCP, int OCOUT, int KK, int PAD, bool RELU, bool LAST>
__global__ __launch_bounds__(256) void k_conv_mfma(
    const ushort* __restrict__ In, const ushort* __restrict__ Wt,
    const float* __restrict__ bias, ushort* __restrict__ Out,
    const float* __restrict__ flow_up, float* __restrict__ fout)
{
    constexpr int MT = OCP / 16;
    constexpr int NCH = ICP / 32;
    constexpr int NT = 4;
    constexpr int NTAP = KK * KK * NCH;
    const int w = threadIdx.x >> 6;
    const int l = threadIdx.x & 63;
    const int lx = l & 15;
    const int lk = l >> 4;
    const int y = blockIdx.x * 2 + (w >> 1);
    const int n0 = (w & 1) * 64;
    const int b = blockIdx.y;

    const ushort* inbase = In + (size_t)b * HH * WW * ICP;

    f32x4 acc[MT][NT];
#pragma unroll
    for (int m = 0; m < MT; m++)
#pragma unroll
        for (int nt = 0; nt < NT; nt++) acc[m][nt] = (f32x4)(0.f);

    bf16x8 abuf[2][MT];
    bf16x8 bbuf[2][NT];

    auto load_tap = [&](int t, int buf) {
        const int kh = t / (KK * NCH);
        const int kw = (t / NCH) % KK;
        const int ch = t % NCH;
        const int k0 = ch * 32 + lk * 8;
        const ushort* wtap = Wt + (size_t)(kh * KK + kw) * OCP * ICP;
#pragma unroll
        for (int m = 0; m < MT; m++)
            abuf[buf][m] = *reinterpret_cast<const bf16x8*>(wtap + (m * 16 + lx) * ICP + k0);
        const int yy = y + kh - PAD;
        const bool yv = (unsigned)yy < (unsigned)HH;
        const ushort* inrow = inbase + (size_t)yy * WW * ICP;
#pragma unroll
        for (int nt = 0; nt < NT; nt++) {
            int xx = n0 + nt * 16 + lx + kw - PAD;
            bf16x8 v = {};
            if (yv && (unsigned)xx < (unsigned)WW)
                v = *reinterpret_cast<const bf16x8*>(inrow + (size_t)xx * ICP + k0);
            bbuf[buf][nt] = v;
        }
    };

    load_tap(0, 0);
#pragma unroll
    for (int t = 0; t < NTAP; t++) {
        if (t + 1 < NTAP) load_tap(t + 1, (t + 1) & 1);
#pragma unroll
        for (int nt = 0; nt < NT; nt++)
#pragma unroll
            for (int m = 0; m < MT; m++)
                acc[m][nt] = __builtin_amdgcn_mfma_f32_16x16x32_bf16(
                    abuf[t & 1][m], bbuf[t & 1][nt], acc[m][nt], 0, 0, 0);
    }

    if (!LAST) {
#pragma unroll
        for (int m = 0; m < MT; m++) {
            const int oc0 = m * 16 + lk * 4;
            float4 bs = *reinterpret_cast<const float4*>(bias + oc0);
#pragma unroll
            for (int nt = 0; nt < NT; nt++) {
                int x = n0 + nt * 16 + lx;
                float v0 = acc[m][nt][0] + bs.x;
                float v1 = acc[m][nt][1] + bs.y;
                float v2 = acc[m][nt][2] + bs.z;
                float v3 = acc[m][nt][3] + bs.w;
                if (RELU) {
                    v0 = (v0 >= 0.f) ? v0 : NEG * v0;
                    v1 = (v1 >= 0.f) ? v1 : NEG * v1;
                    v2 = (v2 >= 0.f) ? v2 : NEG * v2;
                    v3 = (v3 >= 0.f) ? v3 : NEG * v3;
                }
                ushort4 o;
                o.x = f2bf(v0); o.y = f2bf(v1); o.z = f2bf(v2); o.w = f2bf(v3);
                *reinterpret_cast<ushort4*>(Out + (((size_t)(b * HH + y)) * WW + x) * OCOUT + oc0) = o;
            }
        }
    } else {
        if (lk == 0) {
#pragma unroll
            for (int nt = 0; nt < NT; nt++) {
                int x = n0 + nt * 16 + lx;
#pragma unroll
                for (int r = 0; r < 2; r++) {
                    size_t o = (((size_t)(b * 2 + r)) * HH + y) * WW + x;
                    fout[o] = acc[0][nt][r] + bias[r] + flow_up[o];
                }
            }
        }
    }
}

extern "C" void kernel_launch(void* const* d_in, const int* in_sizes, int n_in,
                              void* d_out, int out_size, void* d_ws, size_t ws_size,
                              hipStream_t stream) {
    const float* f1   = (const float*)d_in[0];
    const float* f2   = (const float*)d_in[1];
    const float* flow = (const float*)d_in[2];
    const float* w1   = (const float*)d_in[3];
    const float* b1   = (const float*)d_in[4];
    const float* w2   = (const float*)d_in[5];
    const float* b2   = (const float*)d_in[6];
    const float* w3   = (const float*)d_in[7];
    const float* b3   = (const float*)d_in[8];
    float* out = (float*)d_out;

    char* ws = (char*)d_ws;
    const size_t SZ_FLOWUP = (size_t)BB * 2 * HW * 4;          // 1.0 MB
    const size_t SZ_CT     = (size_t)BB * HW * 64 * 2;         // 16.8 MB
    const size_t SZ_WT1    = (size_t)9 * 64 * 64 * 2;
    const size_t SZ_WT2    = (size_t)9 * 32 * 64 * 2;
    const size_t SZ_WT3    = (size_t)25 * 16 * 32 * 2;
    const size_t SZ_F2G8   = (size_t)BB * HW * CC * 2;         // 33.5 MB

    float*  flow_up = (float*)ws;                         ws += SZ_FLOWUP;
    ushort* Ct      = (ushort*)ws;                        ws += SZ_CT;
    ushort* Wt1     = (ushort*)ws;                        ws += SZ_WT1;
    ushort* Wt2     = (ushort*)ws;                        ws += SZ_WT2;
    ushort* Wt3     = (ushort*)ws;                        ws += SZ_WT3;
    ushort* f2g8    = (ushort*)ws;                        ws += SZ_F2G8;
    ushort* f1g8    = (ushort*)ws;                        // 33.5 MB
    ushort* h1      = f1g8;                               // aliases f1g8 (dead after corr)
    ushort* h2      = (ushort*)((char*)f1g8 + (size_t)BB * HW * 64 * 2);

    k_prep_w<49, 64, 64, 64, 3><<<dim3((9 * 64 * 64 + 255) / 256), dim3(256), 0, stream>>>(w1, Wt1);
    k_prep_w<64, 64, 32, 32, 3><<<dim3((9 * 32 * 64 + 255) / 256), dim3(256), 0, stream>>>(w2, Wt2);
    k_prep_w<32, 32, 2, 16, 5><<<dim3((25 * 16 * 32 + 255) / 256), dim3(256), 0, stream>>>(w3, Wt3);

    k_flow_up<<<dim3(HH, 2, BB), dim3(WW), 0, stream>>>(flow, flow_up);
    k_warp   <<<dim3(4096), dim3(256), 0, stream>>>(f2, flow_up, f2g8);
    k_prep_f1<<<dim3(4096), dim3(256), 0, stream>>>(f1, f1g8);
    k_corr_mfma<<<dim3(2, HH, BB), dim3(256), 0, stream>>>(f1g8, f2g8, Ct);

    k_conv_mfma<64, 64, 64, 3, 1, true,  false><<<dim3(HH / 2, BB), dim3(256), 0, stream>>>(
        Ct, Wt1, b1, h1, nullptr, nullptr);
    k_conv_mfma<64, 32, 32, 3, 1, true,  false><<<dim3(HH / 2, BB), dim3(256), 0, stream>>>(
        h1, Wt2, b2, h2, nullptr, nullptr);
    k_conv_mfma<32, 16, 2,  5, 2, false, true ><<<dim3(HH / 2, BB), dim3(256), 0, stream>>>(
        h2, Wt3, b3, nullptr, flow_up, out);
}

// Round 7
// 204.582 us; speedup vs baseline: 3.0092x; 1.0076x over previous
//
#include <hip/hip_runtime.h>
#include <hip/hip_bf16.h>

#define BB 8
#define CC 128
#define HH 128
#define WW 128
#define HW (HH*WW)
#define MD 3
#define ND 49
#define WARP_WEIGHT 2.5f
#define NEG 0.1f

typedef __attribute__((ext_vector_type(8))) short bf16x8;
typedef __attribute__((ext_vector_type(4))) float f32x4;

__device__ inline ushort f2bf(float f) {
    __hip_bfloat16 h = __float2bfloat16(f);
    return *reinterpret_cast<ushort*>(&h);
}
__device__ inline float bf2f(short s) {
    return __uint_as_float(((uint)(ushort)s) << 16);
}

// g8 layout (f1 only): F[b][y][g][x][8] ushort, g = c/8
#define G8_IDX(b, y, g) ((((size_t)((b) * HH + (y)) * 16) + (g)) * (WW * 8))

// ---------------- flow upsample (bilinear x2, align_corners=False) ----------------
__global__ void k_flow_up(const float* __restrict__ flow, float* __restrict__ flow_up) {
    const int x = threadIdx.x;
    const int y = blockIdx.x;
    const int c = blockIdx.y;
    const int b = blockIdx.z;
    const int Hs = 64, Ws = 64;
    float sy = (y + 0.5f) * 0.5f - 0.5f;
    float sx = (x + 0.5f) * 0.5f - 0.5f;
    float y0f = floorf(sy), x0f = floorf(sx);
    int y0 = (int)y0f, x0 = (int)x0f;
    float wy = sy - y0f, wx = sx - x0f;
    int y0c = min(max(y0, 0), Hs - 1), y1c = min(max(y0 + 1, 0), Hs - 1);
    int x0c = min(max(x0, 0), Ws - 1), x1c = min(max(x0 + 1, 0), Ws - 1);
    const float* src = flow + ((size_t)(b * 2 + c)) * Hs * Ws;
    float v00 = src[y0c * Ws + x0c], v01 = src[y0c * Ws + x1c];
    float v10 = src[y1c * Ws + x0c], v11 = src[y1c * Ws + x1c];
    float v = v00 * (1.f - wx) * (1.f - wy) + v01 * wx * (1.f - wy)
            + v10 * (1.f - wx) * wy + v11 * wx * wy;
    flow_up[((size_t)(b * 2 + c) * HH + y) * WW + x] = v;
}

// ---------------- f2 planar f32 -> channel-last bf16 [b][y][x][128] via LDS ----------------
__global__ __launch_bounds__(256) void k_prep_cl(const float* __restrict__ src,
                                                 ushort* __restrict__ dstcl) {
    __shared__ ushort lds[128][68];          // 64 ch + pad 4 (8B-aligned rows)
    const int y = blockIdx.x & 127;
    const int b = (blockIdx.x >> 7) & 7;
    const int chunk = blockIdx.x >> 10;      // 0..1 (64 channels each)
    {
        const int x = threadIdx.x & 127;
        const int cg = threadIdx.x >> 7;     // 0..1 -> 32 ch each
        const int c0 = chunk * 64 + cg * 32;
        const float* s = src + ((size_t)b * CC + c0) * HW + y * WW + x;
#pragma unroll
        for (int j4 = 0; j4 < 8; j4++) {
            ushort t[4];
#pragma unroll
            for (int u = 0; u < 4; u++) t[u] = f2bf(s[(size_t)(j4 * 4 + u) * HW]);
            *reinterpret_cast<uint2*>(&lds[x][cg * 32 + j4 * 4]) =
                *reinterpret_cast<const uint2*>(t);
        }
    }
    __syncthreads();
    {
        const int xw = threadIdx.x >> 1;
        const int h = threadIdx.x & 1;
        ushort* d = dstcl + (((size_t)(b * HH + y)) * WW + xw) * CC + chunk * 64 + h * 32;
#pragma unroll
        for (int i = 0; i < 8; i++)
            *reinterpret_cast<uint2*>(d + i * 4) =
                *reinterpret_cast<const uint2*>(&lds[xw][h * 32 + i * 4]);
    }
}

// ---------------- backward warp from CL bf16: 16 lanes per pixel ----------------
__global__ __launch_bounds__(256) void k_warp2(const ushort* __restrict__ f2cl,
                                               const float* __restrict__ flow_up,
                                               ushort* __restrict__ f2wcl) {
    const int bid = blockIdx.x;          // 8192
    const int k = bid & 7;               // XCD band
    const int t = bid >> 3;              // 0..1023
    const int xs = t & 7;
    const int y  = k * 16 + ((t >> 3) & 15);
    const int b  = t >> 7;
    const int p  = threadIdx.x >> 4;     // 0..15 pixel in block
    const int g  = threadIdx.x & 15;     // channel group (8 ch)
    const int x  = xs * 16 + p;

    const float fx = flow_up[((size_t)(b * 2 + 0) * HH + y) * WW + x] * WARP_WEIGHT;
    const float fy = flow_up[((size_t)(b * 2 + 1) * HH + y) * WW + x] * WARP_WEIGHT;
    const float sx = (float)x + fx;
    const float sy = (float)y + fy;
    float x0f = floorf(sx), y0f = floorf(sy);
    int x0 = (int)x0f, y0 = (int)y0f;
    float wx = sx - x0f, wy = sy - y0f;
    int x0c = min(max(x0, 0), WW - 1), x1c = min(max(x0 + 1, 0), WW - 1);
    int y0c = min(max(y0, 0), HH - 1), y1c = min(max(y0 + 1, 0), HH - 1);
    bool vx0 = (x0 >= 0) & (x0 < WW);
    bool vx1 = (x0 + 1 >= 0) & (x0 + 1 < WW);
    bool vy0 = (y0 >= 0) & (y0 < HH);
    bool vy1 = (y0 + 1 >= 0) & (y0 + 1 < HH);
    float w00 = (vx0 && vy0) ? (1.f - wx) * (1.f - wy) : 0.f;
    float w01 = (vx1 && vy0) ? wx * (1.f - wy) : 0.f;
    float w10 = (vx0 && vy1) ? (1.f - wx) * wy : 0.f;
    float w11 = (vx1 && vy1) ? wx * wy : 0.f;

    const ushort* base = f2cl + (size_t)b * HW * CC + (size_t)g * 8;
    bf16x8 t00 = *reinterpret_cast<const bf16x8*>(base + ((size_t)y0c * WW + x0c) * CC);
    bf16x8 t01 = *reinterpret_cast<const bf16x8*>(base + ((size_t)y0c * WW + x1c) * CC);
    bf16x8 t10 = *reinterpret_cast<const bf16x8*>(base + ((size_t)y1c * WW + x0c) * CC);
    bf16x8 t11 = *reinterpret_cast<const bf16x8*>(base + ((size_t)y1c * WW + x1c) * CC);

    ushort o[8];
#pragma unroll
    for (int j = 0; j < 8; j++) {
        float v = w00 * bf2f(t00[j]) + w01 * bf2f(t01[j])
                + w10 * bf2f(t10[j]) + w11 * bf2f(t11[j]);
        o[j] = f2bf(v);
    }
    *reinterpret_cast<uint4*>(f2wcl + (((size_t)(b * HH + y)) * WW + x) * CC + g * 8) =
        *reinterpret_cast<const uint4*>(o);
}

// ---------------- f1 planar f32 -> g8 bf16 ----------------
__global__ __launch_bounds__(256) void k_prep_f1(const float* __restrict__ f1,
                                                 ushort* __restrict__ f1g8) {
    const int bid = blockIdx.x;            // 4096
    const int y = bid & 127;
    const int b = (bid >> 7) & 7;
    const int chunk = bid >> 10;           // 0..3
    const int x  = threadIdx.x & 127;
    const int cg = threadIdx.x >> 7;
    const int c0 = chunk * 32 + cg * 16;
    const float* src = f1 + ((size_t)b * CC + c0) * HW + y * WW + x;
#pragma unroll
    for (int gi = 0; gi < 2; gi++) {
        ushort tmp[8];
#pragma unroll
        for (int j = 0; j < 8; j++) tmp[j] = f2bf(src[(size_t)(gi * 8 + j) * HW]);
        *reinterpret_cast<uint4*>(f1g8 + G8_IDX(b, y, (c0 >> 3) + gi) + x * 8) =
            *reinterpret_cast<const uint4*>(tmp);
    }
}

// ---------------- MFMA cost volume (f1 g8, f2w CL) ----------------
__global__ __launch_bounds__(256) void k_corr_mfma(const ushort* __restrict__ f1g8,
                                                   const ushort* __restrict__ f2wcl,
                                                   ushort* __restrict__ Ct) {
    const int w  = threadIdx.x >> 6;
    const int l  = threadIdx.x & 63;
    const int lx = l & 15;
    const int lk = l >> 4;
    const int tile = blockIdx.x * 4 + w;   // 0..7
    const int xa0 = tile * 16;
    const int y = blockIdx.y;
    const int b = blockIdx.z;

    bf16x8 afr[4];
#pragma unroll
    for (int kk = 0; kk < 4; kk++)
        afr[kk] = *reinterpret_cast<const bf16x8*>(
            f1g8 + G8_IDX(b, y, kk * 4 + lk) + (xa0 + lx) * 8);

    ushort* crow = Ct + (((size_t)(b * HH + y)) * WW + xa0) * 64;
    const float scale = 1.f / (float)CC;
    const int xb0 = xa0 - 3 + lx;
    const int xb1 = xa0 + 13 + lx;

    for (int dy = 0; dy < 7; dy++) {
        int yy = y + dy - MD;
        f32x4 acc0 = (f32x4)(0.f), acc1 = (f32x4)(0.f);
        if ((unsigned)yy < (unsigned)HH) {
            const ushort* brow = f2wcl + ((size_t)(b * HH + yy)) * WW * CC;
#pragma unroll
            for (int kk = 0; kk < 4; kk++) {
                const int k0 = kk * 32 + lk * 8;
                bf16x8 b0 = {}, b1 = {};
                if ((unsigned)xb0 < (unsigned)WW)
                    b0 = *reinterpret_cast<const bf16x8*>(brow + (size_t)xb0 * CC + k0);
                if ((unsigned)xb1 < (unsigned)WW)
                    b1 = *reinterpret_cast<const bf16x8*>(brow + (size_t)xb1 * CC + k0);
                acc0 = __builtin_amdgcn_mfma_f32_16x16x32_bf16(afr[kk], b0, acc0, 0, 0, 0);
                acc1 = __builtin_amdgcn_mfma_f32_16x16x32_bf16(afr[kk], b1, acc1, 0, 0, 0);
            }
        }
#pragma unroll
        for (int r = 0; r < 4; r++) {
            int i = lk * 4 + r;
            int d0 = lx - i;
            if (d0 >= 0 && d0 <= 6)
                crow[(size_t)i * 64 + dy * 7 + d0] = f2bf(acc0[r] * scale);
            int d1 = lx - i + 16;
            if (d1 >= 0 && d1 <= 6)
                crow[(size_t)i * 64 + dy * 7 + d1] = f2bf(acc1[r] * scale);
        }
    }
}

// ---------------- weight transpose + bf16: w[OC][IC][K][K] -> Wt[K*K][OCP][ICP] ----------------
template<int IC, int ICP, int OC, int OCP, int KK>
__global__ void k_prep_w(const float* __restrict__ w, ushort* __restrict__ Wt) {
    int e = blockIdx.x * 256 + threadIdx.x;
    const int total = KK * KK * OCP * ICP;
    if (e >= total) return;
    int ic = e % ICP;
    int oc = (e / ICP) % OCP;
    int tap = e / (ICP * OCP);
    int kh = tap / KK, kw = tap % KK;
    float v = 0.f;
    if (oc < OC && ic < IC) v = w[((oc * IC + ic) * KK + kh) * KK + kw];
    Wt[e] = f2bf(v);
}

// ---------------- implicit-GEMM MFMA conv, NT=4, double-buffered tap prefetch ----------------
template<int ICP, int OCP, int OCOUT, int KK, int PAD, bool RELU, bool LAST>
__global__ __launch_bounds__(256) void k_conv_mfma(
    const ushort* __restrict__ In, const ushort* __restrict__ Wt,
    const float* __restrict__ bias, ushort* __restrict__ Out,
    const float* __restrict__ flow_up, float* __restrict__ fout)
{
    constexpr int MT = OCP / 16;
    constexpr int NCH = ICP / 32;
    constexpr int NT = 4;
    constexpr int NTAP = KK * KK * NCH;
    const int w = threadIdx.x >> 6;
    const int l = threadIdx.x & 63;
    const int lx = l & 15;
    const int lk = l >> 4;
    const int y = blockIdx.x * 2 + (w >> 1);
    const int n0 = (w & 1) * 64;
    const int b = blockIdx.y;

    const ushort* inbase = In + (size_t)b * HH * WW * ICP;

    f32x4 acc[MT][NT];
#pragma unroll
    for (int m = 0; m < MT; m++)
#pragma unroll
        for (int nt = 0; nt < NT; nt++) acc[m][nt] = (f32x4)(0.f);

    bf16x8 abuf[2][MT];
    bf16x8 bbuf[2][NT];

    auto load_tap = [&](int t, int buf) {
        const int kh = t / (KK * NCH);
        const int kw = (t / NCH) % KK;
        const int ch = t % NCH;
        const int k0 = ch * 32 + lk * 8;
        const ushort* wtap = Wt + (size_t)(kh * KK + kw) * OCP * ICP;
#pragma unroll
        for (int m = 0; m < MT; m++)
            abuf[buf][m] = *reinterpret_cast<const bf16x8*>(wtap + (m * 16 + lx) * ICP + k0);
        const int yy = y + kh - PAD;
        const bool yv = (unsigned)yy < (unsigned)HH;
        const ushort* inrow = inbase + (size_t)yy * WW * ICP;
#pragma unroll
        for (int nt = 0; nt < NT; nt++) {
            int xx = n0 + nt * 16 + lx + kw - PAD;
            bf16x8 v = {};
            if (yv && (unsigned)xx < (unsigned)WW)
                v = *reinterpret_cast<const bf16x8*>(inrow + (size_t)xx * ICP + k0);
            bbuf[buf][nt] = v;
        }
    };

    load_tap(0, 0);
#pragma unroll
    for (int t = 0; t < NTAP; t++) {
        if (t + 1 < NTAP) load_tap(t + 1, (t + 1) & 1);
#pragma unroll
        for (int nt = 0; nt < NT; nt++)
#pragma unroll
            for (int m = 0; m < MT; m++)
                acc[m][nt] = __builtin_amdgcn_mfma_f32_16x16x32_bf16(
                    abuf[t & 1][m], bbuf[t & 1][nt], acc[m][nt], 0, 0, 0);
    }

    if (!LAST) {
#pragma unroll
        for (int m = 0; m < MT; m++) {
            const int oc0 = m * 16 + lk * 4;
            float4 bs = *reinterpret_cast<const float4*>(bias + oc0);
#pragma unroll
            for (int nt = 0; nt < NT; nt++) {
                int x = n0 + nt * 16 + lx;
                float v0 = acc[m][nt][0] + bs.x;
                float v1 = acc[m][nt][1] + bs.y;
                float v2 = acc[m][nt][2] + bs.z;
                float v3 = acc[m][nt][3] + bs.w;
                if (RELU) {
                    v0 = (v0 >= 0.f) ? v0 : NEG * v0;
                    v1 = (v1 >= 0.f) ? v1 : NEG * v1;
                    v2 = (v2 >= 0.f) ? v2 : NEG * v2;
                    v3 = (v3 >= 0.f) ? v3 : NEG * v3;
                }
                ushort4 o;
                o.x = f2bf(v0); o.y = f2bf(v1); o.z = f2bf(v2); o.w = f2bf(v3);
                *reinterpret_cast<ushort4*>(Out + (((size_t)(b * HH + y)) * WW + x) * OCOUT + oc0) = o;
            }
        }
    } else {
        if (lk == 0) {
#pragma unroll
            for (int nt = 0; nt < NT; nt++) {
                int x = n0 + nt * 16 + lx;
#pragma unroll
                for (int r = 0; r < 2; r++) {
                    size_t o = (((size_t)(b * 2 + r)) * HH + y) * WW + x;
                    fout[o] = acc[0][nt][r] + bias[r] + flow_up[o];
                }
            }
        }
    }
}

extern "C" void kernel_launch(void* const* d_in, const int* in_sizes, int n_in,
                              void* d_out, int out_size, void* d_ws, size_t ws_size,
                              hipStream_t stream) {
    const float* f1   = (const float*)d_in[0];
    const float* f2   = (const float*)d_in[1];
    const float* flow = (const float*)d_in[2];
    const float* w1   = (const float*)d_in[3];
    const float* b1   = (const float*)d_in[4];
    const float* w2   = (const float*)d_in[5];
    const float* b2   = (const float*)d_in[6];
    const float* w3   = (const float*)d_in[7];
    const float* b3   = (const float*)d_in[8];
    float* out = (float*)d_out;

    char* ws = (char*)d_ws;
    const size_t SZ_FLOWUP = (size_t)BB * 2 * HW * 4;          // 1.0 MB
    const size_t SZ_CT     = (size_t)BB * HW * 64 * 2;         // 16.8 MB
    const size_t SZ_WT1    = (size_t)9 * 64 * 64 * 2;
    const size_t SZ_WT2    = (size_t)9 * 32 * 64 * 2;
    const size_t SZ_WT3    = (size_t)25 * 16 * 32 * 2;
    const size_t SZ_BUF    = (size_t)BB * HW * CC * 2;         // 33.5 MB

    float*  flow_up = (float*)ws;                         ws += SZ_FLOWUP;
    ushort* Ct      = (ushort*)ws;                        ws += SZ_CT;
    ushort* Wt1     = (ushort*)ws;                        ws += SZ_WT1;
    ushort* Wt2     = (ushort*)ws;                        ws += SZ_WT2;
    ushort* Wt3     = (ushort*)ws;                        ws += SZ_WT3;
    ushort* f2wcl   = (ushort*)ws;                        ws += SZ_BUF;   // bufB
    ushort* bufA    = (ushort*)ws;                        // f2cl -> f1g8 -> h1/h2
    ushort* f2cl    = bufA;
    ushort* f1g8    = bufA;
    ushort* h1      = bufA;
    ushort* h2      = (ushort*)((char*)bufA + (size_t)BB * HW * 64 * 2);

    k_prep_w<49, 64, 64, 64, 3><<<dim3((9 * 64 * 64 + 255) / 256), dim3(256), 0, stream>>>(w1, Wt1);
    k_prep_w<64, 64, 32, 32, 3><<<dim3((9 * 32 * 64 + 255) / 256), dim3(256), 0, stream>>>(w2, Wt2);
    k_prep_w<32, 32, 2, 16, 5><<<dim3((25 * 16 * 32 + 255) / 256), dim3(256), 0, stream>>>(w3, Wt3);

    k_flow_up<<<dim3(HH, 2, BB), dim3(WW), 0, stream>>>(flow, flow_up);
    k_prep_cl<<<dim3(2048), dim3(256), 0, stream>>>(f2, f2cl);          // f2 -> CL bf16 (bufA)
    k_warp2  <<<dim3(8192), dim3(256), 0, stream>>>(f2cl, flow_up, f2wcl);
    k_prep_f1<<<dim3(4096), dim3(256), 0, stream>>>(f1, f1g8);          // overwrites bufA (f2cl dead)
    k_corr_mfma<<<dim3(2, HH, BB), dim3(256), 0, stream>>>(f1g8, f2wcl, Ct);

    k_conv_mfma<64, 64, 64, 3, 1, true,  false><<<dim3(HH / 2, BB), dim3(256), 0, stream>>>(
        Ct, Wt1, b1, h1, nullptr, nullptr);
    k_conv_mfma<64, 32, 32, 3, 1, true,  false><<<dim3(HH / 2, BB), dim3(256), 0, stream>>>(
        h1, Wt2, b2, h2, nullptr, nullptr);
    k_conv_mfma<32, 16, 2,  5, 2, false, true ><<<dim3(HH / 2, BB), dim3(256), 0, stream>>>(
        h2, Wt3, b3, nullptr, flow_up, out);
}

// Round 8
// 185.678 us; speedup vs baseline: 3.3155x; 1.1018x over previous
//
#include <hip/hip_runtime.h>
#include <hip/hip_bf16.h>

#define BB 8
#define CC 128
#define HH 128
#define WW 128
#define HW (HH*WW)
#define MD 3
#define ND 49
#define WARP_WEIGHT 2.5f
#define NEG 0.1f

typedef __attribute__((ext_vector_type(8))) short bf16x8;
typedef __attribute__((ext_vector_type(4))) float f32x4;

__device__ inline ushort f2bf(float f) {
    __hip_bfloat16 h = __float2bfloat16(f);
    return *reinterpret_cast<ushort*>(&h);
}
__device__ inline float bf2f(short s) {
    return __uint_as_float(((uint)(ushort)s) << 16);
}

// g8 layout: F[b][y][g][x][8] ushort, g = c/8
#define G8_IDX(b, y, g) ((((size_t)((b) * HH + (y)) * 16) + (g)) * (WW * 8))

// ---------------- flow upsample (bilinear x2, align_corners=False) ----------------
__global__ void k_flow_up(const float* __restrict__ flow, float* __restrict__ flow_up) {
    const int x = threadIdx.x;
    const int y = blockIdx.x;
    const int c = blockIdx.y;
    const int b = blockIdx.z;
    const int Hs = 64, Ws = 64;
    float sy = (y + 0.5f) * 0.5f - 0.5f;
    float sx = (x + 0.5f) * 0.5f - 0.5f;
    float y0f = floorf(sy), x0f = floorf(sx);
    int y0 = (int)y0f, x0 = (int)x0f;
    float wy = sy - y0f, wx = sx - x0f;
    int y0c = min(max(y0, 0), Hs - 1), y1c = min(max(y0 + 1, 0), Hs - 1);
    int x0c = min(max(x0, 0), Ws - 1), x1c = min(max(x0 + 1, 0), Ws - 1);
    const float* src = flow + ((size_t)(b * 2 + c)) * Hs * Ws;
    float v00 = src[y0c * Ws + x0c], v01 = src[y0c * Ws + x1c];
    float v10 = src[y1c * Ws + x0c], v11 = src[y1c * Ws + x1c];
    float v = v00 * (1.f - wx) * (1.f - wy) + v01 * wx * (1.f - wy)
            + v10 * (1.f - wx) * wy + v11 * wx * wy;
    flow_up[((size_t)(b * 2 + c) * HH + y) * WW + x] = v;
}

// ---------------- f2 planar f32 -> channel-last bf16 [b][y][x][128] via LDS ----------------
__global__ __launch_bounds__(256) void k_prep_cl(const float* __restrict__ src,
                                                 ushort* __restrict__ dstcl) {
    __shared__ ushort lds[128][68];
    const int y = blockIdx.x & 127;
    const int b = (blockIdx.x >> 7) & 7;
    const int chunk = blockIdx.x >> 10;      // 0..1 (64 channels each)
    {
        const int x = threadIdx.x & 127;
        const int cg = threadIdx.x >> 7;     // 0..1 -> 32 ch each
        const int c0 = chunk * 64 + cg * 32;
        const float* s = src + ((size_t)b * CC + c0) * HW + y * WW + x;
#pragma unroll
        for (int j4 = 0; j4 < 8; j4++) {
            ushort t[4];
#pragma unroll
            for (int u = 0; u < 4; u++) t[u] = f2bf(s[(size_t)(j4 * 4 + u) * HW]);
            *reinterpret_cast<uint2*>(&lds[x][cg * 32 + j4 * 4]) =
                *reinterpret_cast<const uint2*>(t);
        }
    }
    __syncthreads();
    {
        const int xw = threadIdx.x >> 1;
        const int h = threadIdx.x & 1;
        ushort* d = dstcl + (((size_t)(b * HH + y)) * WW + xw) * CC + chunk * 64 + h * 32;
#pragma unroll
        for (int i = 0; i < 8; i++)
            *reinterpret_cast<uint2*>(d + i * 4) =
                *reinterpret_cast<const uint2*>(&lds[xw][h * 32 + i * 4]);
    }
}

// ---------------- backward warp: CL gather -> g8 store ----------------
__global__ __launch_bounds__(256) void k_warp2(const ushort* __restrict__ f2cl,
                                               const float* __restrict__ flow_up,
                                               ushort* __restrict__ f2wg8) {
    const int bid = blockIdx.x;          // 8192
    const int k = bid & 7;               // XCD band
    const int t = bid >> 3;              // 0..1023
    const int xs = t & 7;
    const int y  = k * 16 + ((t >> 3) & 15);
    const int b  = t >> 7;
    const int p  = threadIdx.x >> 4;     // pixel in block (0..15)
    const int g  = threadIdx.x & 15;     // channel group (8 ch)
    const int x  = xs * 16 + p;

    const float fx = flow_up[((size_t)(b * 2 + 0) * HH + y) * WW + x] * WARP_WEIGHT;
    const float fy = flow_up[((size_t)(b * 2 + 1) * HH + y) * WW + x] * WARP_WEIGHT;
    const float sx = (float)x + fx;
    const float sy = (float)y + fy;
    float x0f = floorf(sx), y0f = floorf(sy);
    int x0 = (int)x0f, y0 = (int)y0f;
    float wx = sx - x0f, wy = sy - y0f;
    int x0c = min(max(x0, 0), WW - 1), x1c = min(max(x0 + 1, 0), WW - 1);
    int y0c = min(max(y0, 0), HH - 1), y1c = min(max(y0 + 1, 0), HH - 1);
    bool vx0 = (x0 >= 0) & (x0 < WW);
    bool vx1 = (x0 + 1 >= 0) & (x0 + 1 < WW);
    bool vy0 = (y0 >= 0) & (y0 < HH);
    bool vy1 = (y0 + 1 >= 0) & (y0 + 1 < HH);
    float w00 = (vx0 && vy0) ? (1.f - wx) * (1.f - wy) : 0.f;
    float w01 = (vx1 && vy0) ? wx * (1.f - wy) : 0.f;
    float w10 = (vx0 && vy1) ? (1.f - wx) * wy : 0.f;
    float w11 = (vx1 && vy1) ? wx * wy : 0.f;

    const ushort* base = f2cl + (size_t)b * HW * CC + (size_t)g * 8;
    bf16x8 t00 = *reinterpret_cast<const bf16x8*>(base + ((size_t)y0c * WW + x0c) * CC);
    bf16x8 t01 = *reinterpret_cast<const bf16x8*>(base + ((size_t)y0c * WW + x1c) * CC);
    bf16x8 t10 = *reinterpret_cast<const bf16x8*>(base + ((size_t)y1c * WW + x0c) * CC);
    bf16x8 t11 = *reinterpret_cast<const bf16x8*>(base + ((size_t)y1c * WW + x1c) * CC);

    ushort o[8];
#pragma unroll
    for (int j = 0; j < 8; j++) {
        float v = w00 * bf2f(t00[j]) + w01 * bf2f(t01[j])
                + w10 * bf2f(t10[j]) + w11 * bf2f(t11[j]);
        o[j] = f2bf(v);
    }
    *reinterpret_cast<uint4*>(f2wg8 + G8_IDX(b, y, g) + x * 8) =
        *reinterpret_cast<const uint4*>(o);
}

// ---------------- f1 planar f32 -> g8 bf16 ----------------
__global__ __launch_bounds__(256) void k_prep_f1(const float* __restrict__ f1,
                                                 ushort* __restrict__ f1g8) {
    const int bid = blockIdx.x;            // 4096
    const int y = bid & 127;
    const int b = (bid >> 7) & 7;
    const int chunk = bid >> 10;           // 0..3
    const int x  = threadIdx.x & 127;
    const int cg = threadIdx.x >> 7;
    const int c0 = chunk * 32 + cg * 16;
    const float* src = f1 + ((size_t)b * CC + c0) * HW + y * WW + x;
#pragma unroll
    for (int gi = 0; gi < 2; gi++) {
        ushort tmp[8];
#pragma unroll
        for (int j = 0; j < 8; j++) tmp[j] = f2bf(src[(size_t)(gi * 8 + j) * HW]);
        *reinterpret_cast<uint4*>(f1g8 + G8_IDX(b, y, (c0 >> 3) + gi) + x * 8) =
            *reinterpret_cast<const uint4*>(tmp);
    }
}

// ---------------- MFMA cost volume (g8 inputs), one row per 512-thread block ----------------
// XCD-banded: b = bid&7 (one batch per XCD), y = bid>>3 ascending -> sliding 7-row
// window stays in the XCD's L2.
__global__ __launch_bounds__(512) void k_corr_mfma(const ushort* __restrict__ f1g8,
                                                   const ushort* __restrict__ f2g8,
                                                   ushort* __restrict__ Ct) {
    const int b = blockIdx.x & 7;
    const int y = blockIdx.x >> 3;
    const int w  = threadIdx.x >> 6;       // 0..7 x-tile
    const int l  = threadIdx.x & 63;
    const int lx = l & 15;
    const int lk = l >> 4;
    const int xa0 = w * 16;

    bf16x8 afr[4];
#pragma unroll
    for (int kk = 0; kk < 4; kk++)
        afr[kk] = *reinterpret_cast<const bf16x8*>(
            f1g8 + G8_IDX(b, y, kk * 4 + lk) + (xa0 + lx) * 8);

    ushort* crow = Ct + (((size_t)(b * HH + y)) * WW + xa0) * 64;
    const float scale = 1.f / (float)CC;
    const int xb0 = xa0 - 3 + lx;
    const int xb1 = xa0 + 13 + lx;

    for (int dy = 0; dy < 7; dy++) {
        int yy = y + dy - MD;
        f32x4 acc0 = (f32x4)(0.f), acc1 = (f32x4)(0.f);
        if ((unsigned)yy < (unsigned)HH) {
#pragma unroll
            for (int kk = 0; kk < 4; kk++) {
                const ushort* grp = f2g8 + G8_IDX(b, yy, kk * 4 + lk);
                bf16x8 b0 = {}, b1 = {};
                if ((unsigned)xb0 < (unsigned)WW)
                    b0 = *reinterpret_cast<const bf16x8*>(grp + xb0 * 8);
                if ((unsigned)xb1 < (unsigned)WW)
                    b1 = *reinterpret_cast<const bf16x8*>(grp + xb1 * 8);
                acc0 = __builtin_amdgcn_mfma_f32_16x16x32_bf16(afr[kk], b0, acc0, 0, 0, 0);
                acc1 = __builtin_amdgcn_mfma_f32_16x16x32_bf16(afr[kk], b1, acc1, 0, 0, 0);
            }
        }
#pragma unroll
        for (int r = 0; r < 4; r++) {
            int i = lk * 4 + r;
            int d0 = lx - i;
            if (d0 >= 0 && d0 <= 6)
                crow[(size_t)i * 64 + dy * 7 + d0] = f2bf(acc0[r] * scale);
            int d1 = lx - i + 16;
            if (d1 >= 0 && d1 <= 6)
                crow[(size_t)i * 64 + dy * 7 + d1] = f2bf(acc1[r] * scale);
        }
    }
}

// ---------------- weight transpose + bf16: w[OC][IC][K][K] -> Wt[K*K][OCP][ICP] ----------------
template<int IC, int ICP, int OC, int OCP, int KK>
__global__ void k_prep_w(const float* __restrict__ w, ushort* __restrict__ Wt) {
    int e = blockIdx.x * 256 + threadIdx.x;
    const int total = KK * KK * OCP * ICP;
    if (e >= total) return;
    int ic = e % ICP;
    int oc = (e / ICP) % OCP;
    int tap = e / (ICP * OCP);
    int kh = tap / KK, kw = tap % KK;
    float v = 0.f;
    if (oc < OC && ic < IC) v = w[((oc * IC + ic) * KK + kh) * KK + kw];
    Wt[e] = f2bf(v);
}

// ---------------- implicit-GEMM MFMA conv, NT=4, double-buffered tap prefetch ----------------
template<int ICP, int OCP, int OCOUT, int KK, int PAD, bool RELU, bool LAST>
__global__ __launch_bounds__(256) void k_conv_mfma(
    const ushort* __restrict__ In, const ushort* __restrict__ Wt,
    const float* __restrict__ bias, ushort* __restrict__ Out,
    const float* __restrict__ flow_up, float* __restrict__ fout)
{
    constexpr int MT = OCP / 16;
    constexpr int NCH = ICP / 32;
    constexpr int NT = 4;
    constexpr int NTAP = KK * KK * NCH;
    const int w = threadIdx.x >> 6;
    const int l = threadIdx.x & 63;
    const int lx = l & 15;
    const int lk = l >> 4;
    const int y = blockIdx.x * 2 + (w >> 1);
    const int n0 = (w & 1) * 64;
    const int b = blockIdx.y;

    const ushort* inbase = In + (size_t)b * HH * WW * ICP;

    f32x4 acc[MT][NT];
#pragma unroll
    for (int m = 0; m < MT; m++)
#pragma unroll
        for (int nt = 0; nt < NT; nt++) acc[m][nt] = (f32x4)(0.f);

    bf16x8 abuf[2][MT];
    bf16x8 bbuf[2][NT];

    auto load_tap = [&](int t, int buf) {
        const int kh = t / (KK * NCH);
        const int kw = (t / NCH) % KK;
        const int ch = t % NCH;
        const int k0 = ch * 32 + lk * 8;
        const ushort* wtap = Wt + (size_t)(kh * KK + kw) * OCP * ICP;
#pragma unroll
        for (int m = 0; m < MT; m++)
            abuf[buf][m] = *reinterpret_cast<const bf16x8*>(wtap + (m * 16 + lx) * ICP + k0);
        const int yy = y + kh - PAD;
        const bool yv = (unsigned)yy < (unsigned)HH;
        const ushort* inrow = inbase + (size_t)yy * WW * ICP;
#pragma unroll
        for (int nt = 0; nt < NT; nt++) {
            int xx = n0 + nt * 16 + lx + kw - PAD;
            bf16x8 v = {};
            if (yv && (unsigned)xx < (unsigned)WW)
                v = *reinterpret_cast<const bf16x8*>(inrow + (size_t)xx * ICP + k0);
            bbuf[buf][nt] = v;
        }
    };

    load_tap(0, 0);
#pragma unroll
    for (int t = 0; t < NTAP; t++) {
        if (t + 1 < NTAP) load_tap(t + 1, (t + 1) & 1);
#pragma unroll
        for (int nt = 0; nt < NT; nt++)
#pragma unroll
            for (int m = 0; m < MT; m++)
                acc[m][nt] = __builtin_amdgcn_mfma_f32_16x16x32_bf16(
                    abuf[t & 1][m], bbuf[t & 1][nt], acc[m][nt], 0, 0, 0);
    }

    if (!LAST) {
#pragma unroll
        for (int m = 0; m < MT; m++) {
            const int oc0 = m * 16 + lk * 4;
            float4 bs = *reinterpret_cast<const float4*>(bias + oc0);
#pragma unroll
            for (int nt = 0; nt < NT; nt++) {
                int x = n0 + nt * 16 + lx;
                float v0 = acc[m][nt][0] + bs.x;
                float v1 = acc[m][nt][1] + bs.y;
                float v2 = acc[m][nt][2] + bs.z;
                float v3 = acc[m][nt][3] + bs.w;
                if (RELU) {
                    v0 = (v0 >= 0.f) ? v0 : NEG * v0;
                    v1 = (v1 >= 0.f) ? v1 : NEG * v1;
                    v2 = (v2 >= 0.f) ? v2 : NEG * v2;
                    v3 = (v3 >= 0.f) ? v3 : NEG * v3;
                }
                ushort4 o;
                o.x = f2bf(v0); o.y = f2bf(v1); o.z = f2bf(v2); o.w = f2bf(v3);
                *reinterpret_cast<ushort4*>(Out + (((size_t)(b * HH + y)) * WW + x) * OCOUT + oc0) = o;
            }
        }
    } else {
        if (lk == 0) {
#pragma unroll
            for (int nt = 0; nt < NT; nt++) {
                int x = n0 + nt * 16 + lx;
#pragma unroll
                for (int r = 0; r < 2; r++) {
                    size_t o = (((size_t)(b * 2 + r)) * HH + y) * WW + x;
                    fout[o] = acc[0][nt][r] + bias[r] + flow_up[o];
                }
            }
        }
    }
}

extern "C" void kernel_launch(void* const* d_in, const int* in_sizes, int n_in,
                              void* d_out, int out_size, void* d_ws, size_t ws_size,
                              hipStream_t stream) {
    const float* f1   = (const float*)d_in[0];
    const float* f2   = (const float*)d_in[1];
    const float* flow = (const float*)d_in[2];
    const float* w1   = (const float*)d_in[3];
    const float* b1   = (const float*)d_in[4];
    const float* w2   = (const float*)d_in[5];
    const float* b2   = (const float*)d_in[6];
    const float* w3   = (const float*)d_in[7];
    const float* b3   = (const float*)d_in[8];
    float* out = (float*)d_out;

    char* ws = (char*)d_ws;
    const size_t SZ_FLOWUP = (size_t)BB * 2 * HW * 4;          // 1.0 MB
    const size_t SZ_CT     = (size_t)BB * HW * 64 * 2;         // 16.8 MB
    const size_t SZ_WT1    = (size_t)9 * 64 * 64 * 2;
    const size_t SZ_WT2    = (size_t)9 * 32 * 64 * 2;
    const size_t SZ_WT3    = (size_t)25 * 16 * 32 * 2;
    const size_t SZ_BUF    = (size_t)BB * HW * CC * 2;         // 33.5 MB

    float*  flow_up = (float*)ws;                         ws += SZ_FLOWUP;
    ushort* Ct      = (ushort*)ws;                        ws += SZ_CT;
    ushort* Wt1     = (ushort*)ws;                        ws += SZ_WT1;
    ushort* Wt2     = (ushort*)ws;                        ws += SZ_WT2;
    ushort* Wt3     = (ushort*)ws;                        ws += SZ_WT3;
    ushort* f2wg8   = (ushort*)ws;                        ws += SZ_BUF;   // bufB
    ushort* bufA    = (ushort*)ws;                        // f2cl -> f1g8 -> h1/h2
    ushort* f2cl    = bufA;
    ushort* f1g8    = bufA;
    ushort* h1      = bufA;
    ushort* h2      = (ushort*)((char*)bufA + (size_t)BB * HW * 64 * 2);

    k_prep_w<49, 64, 64, 64, 3><<<dim3((9 * 64 * 64 + 255) / 256), dim3(256), 0, stream>>>(w1, Wt1);
    k_prep_w<64, 64, 32, 32, 3><<<dim3((9 * 32 * 64 + 255) / 256), dim3(256), 0, stream>>>(w2, Wt2);
    k_prep_w<32, 32, 2, 16, 5><<<dim3((25 * 16 * 32 + 255) / 256), dim3(256), 0, stream>>>(w3, Wt3);

    k_flow_up<<<dim3(HH, 2, BB), dim3(WW), 0, stream>>>(flow, flow_up);
    k_prep_cl<<<dim3(2048), dim3(256), 0, stream>>>(f2, f2cl);
    k_warp2  <<<dim3(8192), dim3(256), 0, stream>>>(f2cl, flow_up, f2wg8);
    k_prep_f1<<<dim3(4096), dim3(256), 0, stream>>>(f1, f1g8);   // overwrites bufA (f2cl dead)
    k_corr_mfma<<<dim3(1024), dim3(512), 0, stream>>>(f1g8, f2wg8, Ct);

    k_conv_mfma<64, 64, 64, 3, 1, true,  false><<<dim3(HH / 2, BB), dim3(256), 0, stream>>>(
        Ct, Wt1, b1, h1, nullptr, nullptr);
    k_conv_mfma<64, 32, 32, 3, 1, true,  false><<<dim3(HH / 2, BB), dim3(256), 0, stream>>>(
        h1, Wt2, b2, h2, nullptr, nullptr);
    k_conv_mfma<32, 16, 2,  5, 2, false, true ><<<dim3(HH / 2, BB), dim3(256), 0, stream>>>(
        h2, Wt3, b3, nullptr, flow_up, out);
}

// Round 9
// 171.746 us; speedup vs baseline: 3.5845x; 1.0811x over previous
//
#include <hip/hip_runtime.h>
#include <hip/hip_bf16.h>

#define BB 8
#define CC 128
#define HH 128
#define WW 128
#define HW (HH*WW)
#define MD 3
#define ND 49
#define WARP_WEIGHT 2.5f
#define NEG 0.1f

typedef __attribute__((ext_vector_type(8))) short bf16x8;
typedef __attribute__((ext_vector_type(4))) float f32x4;

__device__ inline ushort f2bf(float f) {
    __hip_bfloat16 h = __float2bfloat16(f);
    return *reinterpret_cast<ushort*>(&h);
}
__device__ inline float bf2f(short s) {
    return __uint_as_float(((uint)(ushort)s) << 16);
}

// g8 layout: F[b][y][g][x][8] ushort, g = c/8
#define G8_IDX(b, y, g) ((((size_t)((b) * HH + (y)) * 16) + (g)) * (WW * 8))

// ---------------- flow upsample (bilinear x2, align_corners=False) ----------------
__global__ void k_flow_up(const float* __restrict__ flow, float* __restrict__ flow_up) {
    const int x = threadIdx.x;
    const int y = blockIdx.x;
    const int c = blockIdx.y;
    const int b = blockIdx.z;
    const int Hs = 64, Ws = 64;
    float sy = (y + 0.5f) * 0.5f - 0.5f;
    float sx = (x + 0.5f) * 0.5f - 0.5f;
    float y0f = floorf(sy), x0f = floorf(sx);
    int y0 = (int)y0f, x0 = (int)x0f;
    float wy = sy - y0f, wx = sx - x0f;
    int y0c = min(max(y0, 0), Hs - 1), y1c = min(max(y0 + 1, 0), Hs - 1);
    int x0c = min(max(x0, 0), Ws - 1), x1c = min(max(x0 + 1, 0), Ws - 1);
    const float* src = flow + ((size_t)(b * 2 + c)) * Hs * Ws;
    float v00 = src[y0c * Ws + x0c], v01 = src[y0c * Ws + x1c];
    float v10 = src[y1c * Ws + x0c], v11 = src[y1c * Ws + x1c];
    float v = v00 * (1.f - wx) * (1.f - wy) + v01 * wx * (1.f - wy)
            + v10 * (1.f - wx) * wy + v11 * wx * wy;
    flow_up[((size_t)(b * 2 + c) * HH + y) * WW + x] = v;
}

// ---------------- f2 planar f32 -> channel-last bf16 [b][y][x][128] via LDS ----------------
__global__ __launch_bounds__(256) void k_prep_cl(const float* __restrict__ src,
                                                 ushort* __restrict__ dstcl) {
    __shared__ ushort lds[128][68];
    const int y = blockIdx.x & 127;
    const int b = (blockIdx.x >> 7) & 7;
    const int chunk = blockIdx.x >> 10;      // 0..1 (64 channels each)
    {
        const int x = threadIdx.x & 127;
        const int cg = threadIdx.x >> 7;     // 0..1 -> 32 ch each
        const int c0 = chunk * 64 + cg * 32;
        const float* s = src + ((size_t)b * CC + c0) * HW + y * WW + x;
#pragma unroll
        for (int j4 = 0; j4 < 8; j4++) {
            ushort t[4];
#pragma unroll
            for (int u = 0; u < 4; u++) t[u] = f2bf(s[(size_t)(j4 * 4 + u) * HW]);
            *reinterpret_cast<uint2*>(&lds[x][cg * 32 + j4 * 4]) =
                *reinterpret_cast<const uint2*>(t);
        }
    }
    __syncthreads();
    {
        const int xw = threadIdx.x >> 1;
        const int h = threadIdx.x & 1;
        ushort* d = dstcl + (((size_t)(b * HH + y)) * WW + xw) * CC + chunk * 64 + h * 32;
#pragma unroll
        for (int i = 0; i < 8; i++)
            *reinterpret_cast<uint2*>(d + i * 4) =
                *reinterpret_cast<const uint2*>(&lds[xw][h * 32 + i * 4]);
    }
}

// ---------------- backward warp: CL gather -> g8 store ----------------
__global__ __launch_bounds__(256) void k_warp2(const ushort* __restrict__ f2cl,
                                               const float* __restrict__ flow_up,
                                               ushort* __restrict__ f2wg8) {
    const int bid = blockIdx.x;          // 8192
    const int k = bid & 7;               // XCD band
    const int t = bid >> 3;              // 0..1023
    const int xs = t & 7;
    const int y  = k * 16 + ((t >> 3) & 15);
    const int b  = t >> 7;
    const int p  = threadIdx.x >> 4;     // pixel in block (0..15)
    const int g  = threadIdx.x & 15;     // channel group (8 ch)
    const int x  = xs * 16 + p;

    const float fx = flow_up[((size_t)(b * 2 + 0) * HH + y) * WW + x] * WARP_WEIGHT;
    const float fy = flow_up[((size_t)(b * 2 + 1) * HH + y) * WW + x] * WARP_WEIGHT;
    const float sx = (float)x + fx;
    const float sy = (float)y + fy;
    float x0f = floorf(sx), y0f = floorf(sy);
    int x0 = (int)x0f, y0 = (int)y0f;
    float wx = sx - x0f, wy = sy - y0f;
    int x0c = min(max(x0, 0), WW - 1), x1c = min(max(x0 + 1, 0), WW - 1);
    int y0c = min(max(y0, 0), HH - 1), y1c = min(max(y0 + 1, 0), HH - 1);
    bool vx0 = (x0 >= 0) & (x0 < WW);
    bool vx1 = (x0 + 1 >= 0) & (x0 + 1 < WW);
    bool vy0 = (y0 >= 0) & (y0 < HH);
    bool vy1 = (y0 + 1 >= 0) & (y0 + 1 < HH);
    float w00 = (vx0 && vy0) ? (1.f - wx) * (1.f - wy) : 0.f;
    float w01 = (vx1 && vy0) ? wx * (1.f - wy) : 0.f;
    float w10 = (vx0 && vy1) ? (1.f - wx) * wy : 0.f;
    float w11 = (vx1 && vy1) ? wx * wy : 0.f;

    const ushort* base = f2cl + (size_t)b * HW * CC + (size_t)g * 8;
    bf16x8 t00 = *reinterpret_cast<const bf16x8*>(base + ((size_t)y0c * WW + x0c) * CC);
    bf16x8 t01 = *reinterpret_cast<const bf16x8*>(base + ((size_t)y0c * WW + x1c) * CC);
    bf16x8 t10 = *reinterpret_cast<const bf16x8*>(base + ((size_t)y1c * WW + x0c) * CC);
    bf16x8 t11 = *reinterpret_cast<const bf16x8*>(base + ((size_t)y1c * WW + x1c) * CC);

    ushort o[8];
#pragma unroll
    for (int j = 0; j < 8; j++) {
        float v = w00 * bf2f(t00[j]) + w01 * bf2f(t01[j])
                + w10 * bf2f(t10[j]) + w11 * bf2f(t11[j]);
        o[j] = f2bf(v);
    }
    *reinterpret_cast<uint4*>(f2wg8 + G8_IDX(b, y, g) + x * 8) =
        *reinterpret_cast<const uint4*>(o);
}

// ---------------- f1 planar f32 -> g8 bf16 ----------------
__global__ __launch_bounds__(256) void k_prep_f1(const float* __restrict__ f1,
                                                 ushort* __restrict__ f1g8) {
    const int bid = blockIdx.x;            // 4096
    const int y = bid & 127;
    const int b = (bid >> 7) & 7;
    const int chunk = bid >> 10;           // 0..3
    const int x  = threadIdx.x & 127;
    const int cg = threadIdx.x >> 7;
    const int c0 = chunk * 32 + cg * 16;
    const float* src = f1 + ((size_t)b * CC + c0) * HW + y * WW + x;
#pragma unroll
    for (int gi = 0; gi < 2; gi++) {
        ushort tmp[8];
#pragma unroll
        for (int j = 0; j < 8; j++) tmp[j] = f2bf(src[(size_t)(gi * 8 + j) * HW]);
        *reinterpret_cast<uint4*>(f1g8 + G8_IDX(b, y, (c0 >> 3) + gi) + x * 8) =
            *reinterpret_cast<const uint4*>(tmp);
    }
}

// ---------------- MFMA cost volume v3: 4 y-rows per block, LDS-staged output ----------------
// grid: 256 blocks = b(8, XCD-banded) x yq(32). Block: 8 waves = 8 x-tiles.
// B window yy = y0-3 .. y0+6 swept once (static unroll), fragments reused for
// up to 4 output rows; double-buffered prefetch. Ct written via LDS, coalesced.
__global__ __launch_bounds__(512) void k_corr_mfma(const ushort* __restrict__ f1g8,
                                                   const ushort* __restrict__ f2g8,
                                                   ushort* __restrict__ Ct) {
    __shared__ ushort cstage[4][128][68];   // 69.6 KB, stride 136B (2-way-free banks)
    const int b  = blockIdx.x & 7;
    const int yq = blockIdx.x >> 3;
    const int y0 = yq * 4;
    const int w  = threadIdx.x >> 6;        // x-tile 0..7
    const int l  = threadIdx.x & 63;
    const int lx = l & 15;
    const int lk = l >> 4;
    const int xa0 = w * 16;

    // zero channels 48..63 (conv1 weights are 0 there, but LDS garbage could be NaN)
    {
        const int yl = threadIdx.x >> 7;
        const int px = threadIdx.x & 127;
        uint2 z = {0u, 0u};
#pragma unroll
        for (int j = 0; j < 4; j++)
            *reinterpret_cast<uint2*>(&cstage[yl][px][48 + j * 4]) = z;
    }
    __syncthreads();

    // A fragments for 4 rows
    bf16x8 afr[4][4];
#pragma unroll
    for (int yl = 0; yl < 4; yl++)
#pragma unroll
        for (int kk = 0; kk < 4; kk++)
            afr[yl][kk] = *reinterpret_cast<const bf16x8*>(
                f1g8 + G8_IDX(b, y0 + yl, kk * 4 + lk) + (xa0 + lx) * 8);

    const int xb0 = xa0 - 3 + lx;
    const int xb1 = xa0 + 13 + lx;
    const float scale = 1.f / (float)CC;

    bf16x8 bb[2][8];   // [buf][kk*2+tile]
    auto load_b = [&](int yyi, int buf) {
        const int yy = y0 - 3 + yyi;
        const bool yv = (unsigned)yy < (unsigned)HH;
#pragma unroll
        for (int kk = 0; kk < 4; kk++) {
            const ushort* grp = f2g8 + G8_IDX(b, yy, kk * 4 + lk);
            bf16x8 b0 = {}, b1 = {};
            if (yv && (unsigned)xb0 < (unsigned)WW)
                b0 = *reinterpret_cast<const bf16x8*>(grp + xb0 * 8);
            if (yv && (unsigned)xb1 < (unsigned)WW)
                b1 = *reinterpret_cast<const bf16x8*>(grp + xb1 * 8);
            bb[buf][kk * 2 + 0] = b0;
            bb[buf][kk * 2 + 1] = b1;
        }
    };

    load_b(0, 0);
#pragma unroll
    for (int yyi = 0; yyi < 10; yyi++) {
        if (yyi + 1 < 10) load_b(yyi + 1, (yyi + 1) & 1);
#pragma unroll
        for (int yl = 0; yl < 4; yl++) {
            const int dy = yyi - yl;
            if (dy < 0 || dy > 6) continue;          // static
            f32x4 acc0 = (f32x4)(0.f), acc1 = (f32x4)(0.f);
#pragma unroll
            for (int kk = 0; kk < 4; kk++) {
                acc0 = __builtin_amdgcn_mfma_f32_16x16x32_bf16(
                    afr[yl][kk], bb[yyi & 1][kk * 2 + 0], acc0, 0, 0, 0);
                acc1 = __builtin_amdgcn_mfma_f32_16x16x32_bf16(
                    afr[yl][kk], bb[yyi & 1][kk * 2 + 1], acc1, 0, 0, 0);
            }
#pragma unroll
            for (int r = 0; r < 4; r++) {
                const int i = lk * 4 + r;
                const int d0 = lx - i;
                if (d0 >= 0 && d0 <= 6)
                    cstage[yl][xa0 + i][dy * 7 + d0] = f2bf(acc0[r] * scale);
                const int d1 = lx - i + 16;
                if (d1 >= 0 && d1 <= 6)
                    cstage[yl][xa0 + i][dy * 7 + d1] = f2bf(acc1[r] * scale);
            }
        }
    }
    __syncthreads();

    // coalesced dump: thread -> (yl, px), 64 ch = 16 x uint2
    {
        const int yl = threadIdx.x >> 7;
        const int px = threadIdx.x & 127;
        ushort* dst = Ct + (((size_t)(b * HH + y0 + yl)) * WW + px) * 64;
#pragma unroll
        for (int j = 0; j < 16; j++)
            *reinterpret_cast<uint2*>(dst + j * 4) =
                *reinterpret_cast<const uint2*>(&cstage[yl][px][j * 4]);
    }
}

// ---------------- weight transpose + bf16: w[OC][IC][K][K] -> Wt[K*K][OCP][ICP] ----------------
template<int IC, int ICP, int OC, int OCP, int KK>
__global__ void k_prep_w(const float* __restrict__ w, ushort* __restrict__ Wt) {
    int e = blockIdx.x * 256 + threadIdx.x;
    const int total = KK * KK * OCP * ICP;
    if (e >= total) return;
    int ic = e % ICP;
    int oc = (e / ICP) % OCP;
    int tap = e / (ICP * OCP);
    int kh = tap / KK, kw = tap % KK;
    float v = 0.f;
    if (oc < OC && ic < IC) v = w[((oc * IC + ic) * KK + kh) * KK + kw];
    Wt[e] = f2bf(v);
}

// ---------------- implicit-GEMM MFMA conv, NT=4, double-buffered tap prefetch ----------------
template<int ICP, int OCP, int OCOUT, int KK, int PAD, bool RELU, bool LAST>
__global__ __launch_bounds__(256) void k_conv_mfma(
    const ushort* __restrict__ In, const ushort* __restrict__ Wt,
    const float* __restrict__ bias, ushort* __restrict__ Out,
    const float* __restrict__ flow_up, float* __restrict__ fout)
{
    constexpr int MT = OCP / 16;
    constexpr int NCH = ICP / 32;
    constexpr int NT = 4;
    constexpr int NTAP = KK * KK * NCH;
    const int w = threadIdx.x >> 6;
    const int l = threadIdx.x & 63;
    const int lx = l & 15;
    const int lk = l >> 4;
    const int y = blockIdx.x * 2 + (w >> 1);
    const int n0 = (w & 1) * 64;
    const int b = blockIdx.y;

    const ushort* inbase = In + (size_t)b * HH * WW * ICP;

    f32x4 acc[MT][NT];
#pragma unroll
    for (int m = 0; m < MT; m++)
#pragma unroll
        for (int nt = 0; nt < NT; nt++) acc[m][nt] = (f32x4)(0.f);

    bf16x8 abuf[2][MT];
    bf16x8 bbuf[2][NT];

    auto load_tap = [&](int t, int buf) {
        const int kh = t / (KK * NCH);
        const int kw = (t / NCH) % KK;
        const int ch = t % NCH;
        const int k0 = ch * 32 + lk * 8;
        const ushort* wtap = Wt + (size_t)(kh * KK + kw) * OCP * ICP;
#pragma unroll
        for (int m = 0; m < MT; m++)
            abuf[buf][m] = *reinterpret_cast<const bf16x8*>(wtap + (m * 16 + lx) * ICP + k0);
        const int yy = y + kh - PAD;
        const bool yv = (unsigned)yy < (unsigned)HH;
        const ushort* inrow = inbase + (size_t)yy * WW * ICP;
#pragma unroll
        for (int nt = 0; nt < NT; nt++) {
            int xx = n0 + nt * 16 + lx + kw - PAD;
            bf16x8 v = {};
            if (yv && (unsigned)xx < (unsigned)WW)
                v = *reinterpret_cast<const bf16x8*>(inrow + (size_t)xx * ICP + k0);
            bbuf[buf][nt] = v;
        }
    };

    load_tap(0, 0);
#pragma unroll
    for (int t = 0; t < NTAP; t++) {
        if (t + 1 < NTAP) load_tap(t + 1, (t + 1) & 1);
#pragma unroll
        for (int nt = 0; nt < NT; nt++)
#pragma unroll
            for (int m = 0; m < MT; m++)
                acc[m][nt] = __builtin_amdgcn_mfma_f32_16x16x32_bf16(
                    abuf[t & 1][m], bbuf[t & 1][nt], acc[m][nt], 0, 0, 0);
    }

    if (!LAST) {
#pragma unroll
        for (int m = 0; m < MT; m++) {
            const int oc0 = m * 16 + lk * 4;
            float4 bs = *reinterpret_cast<const float4*>(bias + oc0);
#pragma unroll
            for (int nt = 0; nt < NT; nt++) {
                int x = n0 + nt * 16 + lx;
                float v0 = acc[m][nt][0] + bs.x;
                float v1 = acc[m][nt][1] + bs.y;
                float v2 = acc[m][nt][2] + bs.z;
                float v3 = acc[m][nt][3] + bs.w;
                if (RELU) {
                    v0 = (v0 >= 0.f) ? v0 : NEG * v0;
                    v1 = (v1 >= 0.f) ? v1 : NEG * v1;
                    v2 = (v2 >= 0.f) ? v2 : NEG * v2;
                    v3 = (v3 >= 0.f) ? v3 : NEG * v3;
                }
                ushort4 o;
                o.x = f2bf(v0); o.y = f2bf(v1); o.z = f2bf(v2); o.w = f2bf(v3);
                *reinterpret_cast<ushort4*>(Out + (((size_t)(b * HH + y)) * WW + x) * OCOUT + oc0) = o;
            }
        }
    } else {
        if (lk == 0) {
#pragma unroll
            for (int nt = 0; nt < NT; nt++) {
                int x = n0 + nt * 16 + lx;
#pragma unroll
                for (int r = 0; r < 2; r++) {
                    size_t o = (((size_t)(b * 2 + r)) * HH + y) * WW + x;
                    fout[o] = acc[0][nt][r] + bias[r] + flow_up[o];
                }
            }
        }
    }
}

extern "C" void kernel_launch(void* const* d_in, const int* in_sizes, int n_in,
                              void* d_out, int out_size, void* d_ws, size_t ws_size,
                              hipStream_t stream) {
    const float* f1   = (const float*)d_in[0];
    const float* f2   = (const float*)d_in[1];
    const float* flow = (const float*)d_in[2];
    const float* w1   = (const float*)d_in[3];
    const float* b1   = (const float*)d_in[4];
    const float* w2   = (const float*)d_in[5];
    const float* b2   = (const float*)d_in[6];
    const float* w3   = (const float*)d_in[7];
    const float* b3   = (const float*)d_in[8];
    float* out = (float*)d_out;

    char* ws = (char*)d_ws;
    const size_t SZ_FLOWUP = (size_t)BB * 2 * HW * 4;          // 1.0 MB
    const size_t SZ_CT     = (size_t)BB * HW * 64 * 2;         // 16.8 MB
    const size_t SZ_WT1    = (size_t)9 * 64 * 64 * 2;
    const size_t SZ_WT2    = (size_t)9 * 32 * 64 * 2;
    const size_t SZ_WT3    = (size_t)25 * 16 * 32 * 2;
    const size_t SZ_BUF    = (size_t)BB * HW * CC * 2;         // 33.5 MB

    float*  flow_up = (float*)ws;                         ws += SZ_FLOWUP;
    ushort* Ct      = (ushort*)ws;                        ws += SZ_CT;
    ushort* Wt1     = (ushort*)ws;                        ws += SZ_WT1;
    ushort* Wt2     = (ushort*)ws;                        ws += SZ_WT2;
    ushort* Wt3     = (ushort*)ws;                        ws += SZ_WT3;
    ushort* f2wg8   = (ushort*)ws;                        ws += SZ_BUF;   // bufB
    ushort* bufA    = (ushort*)ws;                        // f2cl -> f1g8 -> h1/h2
    ushort* f2cl    = bufA;
    ushort* f1g8    = bufA;
    ushort* h1      = bufA;
    ushort* h2      = (ushort*)((char*)bufA + (size_t)BB * HW * 64 * 2);

    k_prep_w<49, 64, 64, 64, 3><<<dim3((9 * 64 * 64 + 255) / 256), dim3(256), 0, stream>>>(w1, Wt1);
    k_prep_w<64, 64, 32, 32, 3><<<dim3((9 * 32 * 64 + 255) / 256), dim3(256), 0, stream>>>(w2, Wt2);
    k_prep_w<32, 32, 2, 16, 5><<<dim3((25 * 16 * 32 + 255) / 256), dim3(256), 0, stream>>>(w3, Wt3);

    k_flow_up<<<dim3(HH, 2, BB), dim3(WW), 0, stream>>>(flow, flow_up);
    k_prep_cl<<<dim3(2048), dim3(256), 0, stream>>>(f2, f2cl);
    k_warp2  <<<dim3(8192), dim3(256), 0, stream>>>(f2cl, flow_up, f2wg8);
    k_prep_f1<<<dim3(4096), dim3(256), 0, stream>>>(f1, f1g8);   // overwrites bufA (f2cl dead)
    k_corr_mfma<<<dim3(256), dim3(512), 0, stream>>>(f1g8, f2wg8, Ct);

    k_conv_mfma<64, 64, 64, 3, 1, true,  false><<<dim3(HH / 2, BB), dim3(256), 0, stream>>>(
        Ct, Wt1, b1, h1, nullptr, nullptr);
    k_conv_mfma<64, 32, 32, 3, 1, true,  false><<<dim3(HH / 2, BB), dim3(256), 0, stream>>>(
        h1, Wt2, b2, h2, nullptr, nullptr);
    k_conv_mfma<32, 16, 2,  5, 2, false, true ><<<dim3(HH / 2, BB), dim3(256), 0, stream>>>(
        h2, Wt3, b3, nullptr, flow_up, out);
}

// Round 10
// 169.019 us; speedup vs baseline: 3.6423x; 1.0161x over previous
//
#include <hip/hip_runtime.h>
#include <hip/hip_bf16.h>

#define BB 8
#define CC 128
#define HH 128
#define WW 128
#define HW (HH*WW)
#define MD 3
#define ND 49
#define WARP_WEIGHT 2.5f
#define NEG 0.1f

typedef __attribute__((ext_vector_type(8))) short bf16x8;
typedef __attribute__((ext_vector_type(4))) float f32x4;

__device__ inline ushort f2bf(float f) {
    __hip_bfloat16 h = __float2bfloat16(f);
    return *reinterpret_cast<ushort*>(&h);
}
__device__ inline float bf2f(short s) {
    return __uint_as_float(((uint)(ushort)s) << 16);
}

// g8 layout: F[b][y][g][x][8] ushort, g = c/8
#define G8_IDX(b, y, g) ((((size_t)((b) * HH + (y)) * 16) + (g)) * (WW * 8))

// ---------------- flow upsample (bilinear x2, align_corners=False) ----------------
__global__ void k_flow_up(const float* __restrict__ flow, float* __restrict__ flow_up) {
    const int x = threadIdx.x;
    const int y = blockIdx.x;
    const int c = blockIdx.y;
    const int b = blockIdx.z;
    const int Hs = 64, Ws = 64;
    float sy = (y + 0.5f) * 0.5f - 0.5f;
    float sx = (x + 0.5f) * 0.5f - 0.5f;
    float y0f = floorf(sy), x0f = floorf(sx);
    int y0 = (int)y0f, x0 = (int)x0f;
    float wy = sy - y0f, wx = sx - x0f;
    int y0c = min(max(y0, 0), Hs - 1), y1c = min(max(y0 + 1, 0), Hs - 1);
    int x0c = min(max(x0, 0), Ws - 1), x1c = min(max(x0 + 1, 0), Ws - 1);
    const float* src = flow + ((size_t)(b * 2 + c)) * Hs * Ws;
    float v00 = src[y0c * Ws + x0c], v01 = src[y0c * Ws + x1c];
    float v10 = src[y1c * Ws + x0c], v11 = src[y1c * Ws + x1c];
    float v = v00 * (1.f - wx) * (1.f - wy) + v01 * wx * (1.f - wy)
            + v10 * (1.f - wx) * wy + v11 * wx * wy;
    flow_up[((size_t)(b * 2 + c) * HH + y) * WW + x] = v;
}

// ---------------- f2 planar f32 -> channel-last bf16 [b][y][x][128] via LDS ----------------
__global__ __launch_bounds__(256) void k_prep_cl(const float* __restrict__ src,
                                                 ushort* __restrict__ dstcl) {
    __shared__ ushort lds[128][68];
    const int y = blockIdx.x & 127;
    const int b = (blockIdx.x >> 7) & 7;
    const int chunk = blockIdx.x >> 10;      // 0..1 (64 channels each)
    {
        const int x = threadIdx.x & 127;
        const int cg = threadIdx.x >> 7;     // 0..1 -> 32 ch each
        const int c0 = chunk * 64 + cg * 32;
        const float* s = src + ((size_t)b * CC + c0) * HW + y * WW + x;
#pragma unroll
        for (int j4 = 0; j4 < 8; j4++) {
            ushort t[4];
#pragma unroll
            for (int u = 0; u < 4; u++) t[u] = f2bf(s[(size_t)(j4 * 4 + u) * HW]);
            *reinterpret_cast<uint2*>(&lds[x][cg * 32 + j4 * 4]) =
                *reinterpret_cast<const uint2*>(t);
        }
    }
    __syncthreads();
    {
        const int xw = threadIdx.x >> 1;
        const int h = threadIdx.x & 1;
        ushort* d = dstcl + (((size_t)(b * HH + y)) * WW + xw) * CC + chunk * 64 + h * 32;
#pragma unroll
        for (int i = 0; i < 8; i++)
            *reinterpret_cast<uint2*>(d + i * 4) =
                *reinterpret_cast<const uint2*>(&lds[xw][h * 32 + i * 4]);
    }
}

// ---------------- backward warp: CL gather -> g8 store ----------------
__global__ __launch_bounds__(256) void k_warp2(const ushort* __restrict__ f2cl,
                                               const float* __restrict__ flow_up,
                                               ushort* __restrict__ f2wg8) {
    const int bid = blockIdx.x;          // 8192
    const int k = bid & 7;               // XCD band
    const int t = bid >> 3;              // 0..1023
    const int xs = t & 7;
    const int y  = k * 16 + ((t >> 3) & 15);
    const int b  = t >> 7;
    const int p  = threadIdx.x >> 4;     // pixel in block (0..15)
    const int g  = threadIdx.x & 15;     // channel group (8 ch)
    const int x  = xs * 16 + p;

    const float fx = flow_up[((size_t)(b * 2 + 0) * HH + y) * WW + x] * WARP_WEIGHT;
    const float fy = flow_up[((size_t)(b * 2 + 1) * HH + y) * WW + x] * WARP_WEIGHT;
    const float sx = (float)x + fx;
    const float sy = (float)y + fy;
    float x0f = floorf(sx), y0f = floorf(sy);
    int x0 = (int)x0f, y0 = (int)y0f;
    float wx = sx - x0f, wy = sy - y0f;
    int x0c = min(max(x0, 0), WW - 1), x1c = min(max(x0 + 1, 0), WW - 1);
    int y0c = min(max(y0, 0), HH - 1), y1c = min(max(y0 + 1, 0), HH - 1);
    bool vx0 = (x0 >= 0) & (x0 < WW);
    bool vx1 = (x0 + 1 >= 0) & (x0 + 1 < WW);
    bool vy0 = (y0 >= 0) & (y0 < HH);
    bool vy1 = (y0 + 1 >= 0) & (y0 + 1 < HH);
    float w00 = (vx0 && vy0) ? (1.f - wx) * (1.f - wy) : 0.f;
    float w01 = (vx1 && vy0) ? wx * (1.f - wy) : 0.f;
    float w10 = (vx0 && vy1) ? (1.f - wx) * wy : 0.f;
    float w11 = (vx1 && vy1) ? wx * wy : 0.f;

    const ushort* base = f2cl + (size_t)b * HW * CC + (size_t)g * 8;
    bf16x8 t00 = *reinterpret_cast<const bf16x8*>(base + ((size_t)y0c * WW + x0c) * CC);
    bf16x8 t01 = *reinterpret_cast<const bf16x8*>(base + ((size_t)y0c * WW + x1c) * CC);
    bf16x8 t10 = *reinterpret_cast<const bf16x8*>(base + ((size_t)y1c * WW + x0c) * CC);
    bf16x8 t11 = *reinterpret_cast<const bf16x8*>(base + ((size_t)y1c * WW + x1c) * CC);

    ushort o[8];
#pragma unroll
    for (int j = 0; j < 8; j++) {
        float v = w00 * bf2f(t00[j]) + w01 * bf2f(t01[j])
                + w10 * bf2f(t10[j]) + w11 * bf2f(t11[j]);
        o[j] = f2bf(v);
    }
    *reinterpret_cast<uint4*>(f2wg8 + G8_IDX(b, y, g) + x * 8) =
        *reinterpret_cast<const uint4*>(o);
}

// ---------------- f1 planar f32 -> g8 bf16 ----------------
__global__ __launch_bounds__(256) void k_prep_f1(const float* __restrict__ f1,
                                                 ushort* __restrict__ f1g8) {
    const int bid = blockIdx.x;            // 4096
    const int y = bid & 127;
    const int b = (bid >> 7) & 7;
    const int chunk = bid >> 10;           // 0..3
    const int x  = threadIdx.x & 127;
    const int cg = threadIdx.x >> 7;
    const int c0 = chunk * 32 + cg * 16;
    const float* src = f1 + ((size_t)b * CC + c0) * HW + y * WW + x;
#pragma unroll
    for (int gi = 0; gi < 2; gi++) {
        ushort tmp[8];
#pragma unroll
        for (int j = 0; j < 8; j++) tmp[j] = f2bf(src[(size_t)(gi * 8 + j) * HW]);
        *reinterpret_cast<uint4*>(f1g8 + G8_IDX(b, y, (c0 >> 3) + gi) + x * 8) =
            *reinterpret_cast<const uint4*>(tmp);
    }
}

// ---------------- MFMA cost volume v4: round-8 grid + LDS-staged output + B prefetch ----
// grid: 1024 blocks = b(8, XCD-banded) x y(128). Block: 8 waves = 8 x-tiles, 1 row.
__global__ __launch_bounds__(512) void k_corr_mfma(const ushort* __restrict__ f1g8,
                                                   const ushort* __restrict__ f2g8,
                                                   ushort* __restrict__ Ct) {
    __shared__ ushort cstage[128][68];     // 17.4 KB
    const int b  = blockIdx.x & 7;
    const int y  = blockIdx.x >> 3;
    const int w  = threadIdx.x >> 6;       // x-tile 0..7
    const int l  = threadIdx.x & 63;
    const int lx = l & 15;
    const int lk = l >> 4;
    const int xa0 = w * 16;

    // zero channels 48..63 (48 rewritten by extraction after the barrier)
    {
        const int px = threadIdx.x >> 2;
        const int part = threadIdx.x & 3;
        uint2 z = {0u, 0u};
        *reinterpret_cast<uint2*>(&cstage[px][48 + part * 4]) = z;
    }
    __syncthreads();

    bf16x8 afr[4];
#pragma unroll
    for (int kk = 0; kk < 4; kk++)
        afr[kk] = *reinterpret_cast<const bf16x8*>(
            f1g8 + G8_IDX(b, y, kk * 4 + lk) + (xa0 + lx) * 8);

    const int xb0 = xa0 - 3 + lx;
    const int xb1 = xa0 + 13 + lx;
    const float scale = 1.f / (float)CC;

    bf16x8 bb[2][8];   // [buf][kk*2+tile]
    auto load_b = [&](int dy, int buf) {
        const int yy = y + dy - MD;
        const bool yv = (unsigned)yy < (unsigned)HH;
#pragma unroll
        for (int kk = 0; kk < 4; kk++) {
            const ushort* grp = f2g8 + G8_IDX(b, yy, kk * 4 + lk);
            bf16x8 b0 = {}, b1 = {};
            if (yv && (unsigned)xb0 < (unsigned)WW)
                b0 = *reinterpret_cast<const bf16x8*>(grp + xb0 * 8);
            if (yv && (unsigned)xb1 < (unsigned)WW)
                b1 = *reinterpret_cast<const bf16x8*>(grp + xb1 * 8);
            bb[buf][kk * 2 + 0] = b0;
            bb[buf][kk * 2 + 1] = b1;
        }
    };

    load_b(0, 0);
#pragma unroll
    for (int dy = 0; dy < 7; dy++) {
        if (dy + 1 < 7) load_b(dy + 1, (dy + 1) & 1);
        f32x4 acc0 = (f32x4)(0.f), acc1 = (f32x4)(0.f);
#pragma unroll
        for (int kk = 0; kk < 4; kk++) {
            acc0 = __builtin_amdgcn_mfma_f32_16x16x32_bf16(
                afr[kk], bb[dy & 1][kk * 2 + 0], acc0, 0, 0, 0);
            acc1 = __builtin_amdgcn_mfma_f32_16x16x32_bf16(
                afr[kk], bb[dy & 1][kk * 2 + 1], acc1, 0, 0, 0);
        }
#pragma unroll
        for (int r = 0; r < 4; r++) {
            const int i = lk * 4 + r;
            const int d0 = lx - i;
            if (d0 >= 0 && d0 <= 6)
                cstage[xa0 + i][dy * 7 + d0] = f2bf(acc0[r] * scale);
            const int d1 = lx - i + 16;
            if (d1 >= 0 && d1 <= 6)
                cstage[xa0 + i][dy * 7 + d1] = f2bf(acc1[r] * scale);
        }
    }
    __syncthreads();

    // coalesced dump: thread -> (px, 16-ch part)
    {
        const int px = threadIdx.x >> 2;
        const int part = threadIdx.x & 3;
        ushort* dst = Ct + (((size_t)(b * HH + y)) * WW + px) * 64 + part * 16;
        uint2 t0 = *reinterpret_cast<const uint2*>(&cstage[px][part * 16 + 0]);
        uint2 t1 = *reinterpret_cast<const uint2*>(&cstage[px][part * 16 + 4]);
        uint2 t2 = *reinterpret_cast<const uint2*>(&cstage[px][part * 16 + 8]);
        uint2 t3 = *reinterpret_cast<const uint2*>(&cstage[px][part * 16 + 12]);
        uint4 v0; v0.x = t0.x; v0.y = t0.y; v0.z = t1.x; v0.w = t1.y;
        uint4 v1; v1.x = t2.x; v1.y = t2.y; v1.z = t3.x; v1.w = t3.y;
        *reinterpret_cast<uint4*>(dst) = v0;
        *reinterpret_cast<uint4*>(dst + 8) = v1;
    }
}

// ---------------- weight transpose + bf16: w[OC][IC][K][K] -> Wt[K*K][OCP][ICP] ----------------
template<int IC, int ICP, int OC, int OCP, int KK>
__global__ void k_prep_w(const float* __restrict__ w, ushort* __restrict__ Wt) {
    int e = blockIdx.x * 256 + threadIdx.x;
    const int total = KK * KK * OCP * ICP;
    if (e >= total) return;
    int ic = e % ICP;
    int oc = (e / ICP) % OCP;
    int tap = e / (ICP * OCP);
    int kh = tap / KK, kw = tap % KK;
    float v = 0.f;
    if (oc < OC && ic < IC) v = w[((oc * IC + ic) * KK + kh) * KK + kw];
    Wt[e] = f2bf(v);
}

// ---------------- implicit-GEMM MFMA conv, NT=4, double-buffered tap prefetch ----------------
template<int ICP, int OCP, int OCOUT, int KK, int PAD, bool RELU, bool LAST>
__global__ __launch_bounds__(256) void k_conv_mfma(
    const ushort* __restrict__ In, const ushort* __restrict__ Wt,
    const float* __restrict__ bias, ushort* __restrict__ Out,
    const float* __restrict__ flow_up, float* __restrict__ fout)
{
    constexpr int MT = OCP / 16;
    constexpr int NCH = ICP / 32;
    constexpr int NT = 4;
    constexpr int NTAP = KK * KK * NCH;
    const int w = threadIdx.x >> 6;
    const int l = threadIdx.x & 63;
    const int lx = l & 15;
    const int lk = l >> 4;
    const int y = blockIdx.x * 2 + (w >> 1);
    const int n0 = (w & 1) * 64;
    const int b = blockIdx.y;

    const ushort* inbase = In + (size_t)b * HH * WW * ICP;

    f32x4 acc[MT][NT];
#pragma unroll
    for (int m = 0; m < MT; m++)
#pragma unroll
        for (int nt = 0; nt < NT; nt++) acc[m][nt] = (f32x4)(0.f);

    bf16x8 abuf[2][MT];
    bf16x8 bbuf[2][NT];

    auto load_tap = [&](int t, int buf) {
        const int kh = t / (KK * NCH);
        const int kw = (t / NCH) % KK;
        const int ch = t % NCH;
        const int k0 = ch * 32 + lk * 8;
        const ushort* wtap = Wt + (size_t)(kh * KK + kw) * OCP * ICP;
#pragma unroll
        for (int m = 0; m < MT; m++)
            abuf[buf][m] = *reinterpret_cast<const bf16x8*>(wtap + (m * 16 + lx) * ICP + k0);
        const int yy = y + kh - PAD;
        const bool yv = (unsigned)yy < (unsigned)HH;
        const ushort* inrow = inbase + (size_t)yy * WW * ICP;
#pragma unroll
        for (int nt = 0; nt < NT; nt++) {
            int xx = n0 + nt * 16 + lx + kw - PAD;
            bf16x8 v = {};
            if (yv && (unsigned)xx < (unsigned)WW)
                v = *reinterpret_cast<const bf16x8*>(inrow + (size_t)xx * ICP + k0);
            bbuf[buf][nt] = v;
        }
    };

    load_tap(0, 0);
#pragma unroll
    for (int t = 0; t < NTAP; t++) {
        if (t + 1 < NTAP) load_tap(t + 1, (t + 1) & 1);
#pragma unroll
        for (int nt = 0; nt < NT; nt++)
#pragma unroll
            for (int m = 0; m < MT; m++)
                acc[m][nt] = __builtin_amdgcn_mfma_f32_16x16x32_bf16(
                    abuf[t & 1][m], bbuf[t & 1][nt], acc[m][nt], 0, 0, 0);
    }

    if (!LAST) {
#pragma unroll
        for (int m = 0; m < MT; m++) {
            const int oc0 = m * 16 + lk * 4;
            float4 bs = *reinterpret_cast<const float4*>(bias + oc0);
#pragma unroll
            for (int nt = 0; nt < NT; nt++) {
                int x = n0 + nt * 16 + lx;
                float v0 = acc[m][nt][0] + bs.x;
                float v1 = acc[m][nt][1] + bs.y;
                float v2 = acc[m][nt][2] + bs.z;
                float v3 = acc[m][nt][3] + bs.w;
                if (RELU) {
                    v0 = (v0 >= 0.f) ? v0 : NEG * v0;
                    v1 = (v1 >= 0.f) ? v1 : NEG * v1;
                    v2 = (v2 >= 0.f) ? v2 : NEG * v2;
                    v3 = (v3 >= 0.f) ? v3 : NEG * v3;
                }
                ushort4 o;
                o.x = f2bf(v0); o.y = f2bf(v1); o.z = f2bf(v2); o.w = f2bf(v3);
                *reinterpret_cast<ushort4*>(Out + (((size_t)(b * HH + y)) * WW + x) * OCOUT + oc0) = o;
            }
        }
    } else {
        if (lk == 0) {
#pragma unroll
            for (int nt = 0; nt < NT; nt++) {
                int x = n0 + nt * 16 + lx;
#pragma unroll
                for (int r = 0; r < 2; r++) {
                    size_t o = (((size_t)(b * 2 + r)) * HH + y) * WW + x;
                    fout[o] = acc[0][nt][r] + bias[r] + flow_up[o];
                }
            }
        }
    }
}

extern "C" void kernel_launch(void* const* d_in, const int* in_sizes, int n_in,
                              void* d_out, int out_size, void* d_ws, size_t ws_size,
                              hipStream_t stream) {
    const float* f1   = (const float*)d_in[0];
    const float* f2   = (const float*)d_in[1];
    const float* flow = (const float*)d_in[2];
    const float* w1   = (const float*)d_in[3];
    const float* b1   = (const float*)d_in[4];
    const float* w2   = (const float*)d_in[5];
    const float* b2   = (const float*)d_in[6];
    const float* w3   = (const float*)d_in[7];
    const float* b3   = (const float*)d_in[8];
    float* out = (float*)d_out;

    char* ws = (char*)d_ws;
    const size_t SZ_FLOWUP = (size_t)BB * 2 * HW * 4;          // 1.0 MB
    const size_t SZ_CT     = (size_t)BB * HW * 64 * 2;         // 16.8 MB
    const size_t SZ_WT1    = (size_t)9 * 64 * 64 * 2;
    const size_t SZ_WT2    = (size_t)9 * 32 * 64 * 2;
    const size_t SZ_WT3    = (size_t)25 * 16 * 32 * 2;
    const size_t SZ_BUF    = (size_t)BB * HW * CC * 2;         // 33.5 MB

    float*  flow_up = (float*)ws;                         ws += SZ_FLOWUP;
    ushort* Ct      = (ushort*)ws;                        ws += SZ_CT;
    ushort* Wt1     = (ushort*)ws;                        ws += SZ_WT1;
    ushort* Wt2     = (ushort*)ws;                        ws += SZ_WT2;
    ushort* Wt3     = (ushort*)ws;                        ws += SZ_WT3;
    ushort* f2wg8   = (ushort*)ws;                        ws += SZ_BUF;   // bufB
    ushort* bufA    = (ushort*)ws;                        // f2cl -> f1g8 -> h1/h2
    ushort* f2cl    = bufA;
    ushort* f1g8    = bufA;
    ushort* h1      = bufA;
    ushort* h2      = (ushort*)((char*)bufA + (size_t)BB * HW * 64 * 2);

    k_prep_w<49, 64, 64, 64, 3><<<dim3((9 * 64 * 64 + 255) / 256), dim3(256), 0, stream>>>(w1, Wt1);
    k_prep_w<64, 64, 32, 32, 3><<<dim3((9 * 32 * 64 + 255) / 256), dim3(256), 0, stream>>>(w2, Wt2);
    k_prep_w<32, 32, 2, 16, 5><<<dim3((25 * 16 * 32 + 255) / 256), dim3(256), 0, stream>>>(w3, Wt3);

    k_flow_up<<<dim3(HH, 2, BB), dim3(WW), 0, stream>>>(flow, flow_up);
    k_prep_cl<<<dim3(2048), dim3(256), 0, stream>>>(f2, f2cl);
    k_warp2  <<<dim3(8192), dim3(256), 0, stream>>>(f2cl, flow_up, f2wg8);
    k_prep_f1<<<dim3(4096), dim3(256), 0, stream>>>(f1, f1g8);   // overwrites bufA (f2cl dead)
    k_corr_mfma<<<dim3(1024), dim3(512), 0, stream>>>(f1g8, f2wg8, Ct);

    k_conv_mfma<64, 64, 64, 3, 1, true,  false><<<dim3(HH / 2, BB), dim3(256), 0, stream>>>(
        Ct, Wt1, b1, h1, nullptr, nullptr);
    k_conv_mfma<64, 32, 32, 3, 1, true,  false><<<dim3(HH / 2, BB), dim3(256), 0, stream>>>(
        h1, Wt2, b2, h2, nullptr, nullptr);
    k_conv_mfma<32, 16, 2,  5, 2, false, true ><<<dim3(HH / 2, BB), dim3(256), 0, stream>>>(
        h2, Wt3, b3, nullptr, flow_up, out);
}